// Round 7
// baseline (623.522 us; speedup 1.0000x reference)
//
#include <hip/hip_runtime.h>
#include <math.h>

// ---------------------------------------------------------------------------
// Problem constants
// ---------------------------------------------------------------------------
#define DM    256     // D_MODEL
#define NH    4
#define HD    64
#define TS    40
#define TM1   39
#define BB    32
#define DFF   1024
#define DINO  384
#define NPATCH 256
#define VOCAB 4096

#define NTOK  24960   // 780*32 packed (t, p<=t, b) tokens
#define NQ2   1248    // 39*32

typedef _Float16 f16;
typedef __attribute__((ext_vector_type(8))) _Float16 half8;  // MFMA A/B frag
typedef __attribute__((ext_vector_type(4))) float f32x4;

// ---------------------------------------------------------------------------
// Workspace layout (float offsets). Residual/LN chain stays fp32 (round-3
// lesson). f16 only where the consumer re-rounds anyway.
// ---------------------------------------------------------------------------
#define OFF_EMB    0u          /* f32 1280*256   327680 */
#define OFF_EMBH   327680u     /* f16 1280*256   163840 */
#define OFF_QKV0   491520u     /* f32 1280*768   983040 */
#define OFF_X1     1474560u    /* f32 24960*256  6389760 */
#define OFF_H1     7864320u    /* f32 24960*256  6389760 */
#define OFF_BIG    14254080u   /* 12779520 f: ao0h/ff1h/kv1h (sequential) */
#define OFF_AO1    27033600u   /* f32 1248*256   319488 */
#define OFF_X2     27353088u   /* f32 1248*256   319488 */
#define OFF_FF2    27672576u   /* f32 1248*1024  1277952 */
#define OFF_CTX    28950528u   /* f32 1280*256   327680 */
#define OFF_PPH    29278208u   /* f16 8192*256   1048576 */
#define OFF_CPB    30326784u   /* f32 1280*256   327680 */
#define OFF_U      30654464u   /* f32 1280*256   327680 */
#define OFF_S      30982144u   /* f32 1280(+pad) 2048 */
#define OFF_WQKVH  30984192u   /* f16 768*256    ->  98304 */
#define OFF_WQ1H   31082496u   /* f16 256*256    ->  32768 */
#define OFF_KVWH   31115264u   /* f16 512*256    ->  65536 */
#define OFF_WOH    31180800u   /* f16 256*256    ->  32768 */
#define OFF_L1WH   31213568u   /* f16 1024*256   -> 131072 */
#define OFF_L2WH   31344640u   /* f16 256*1024   -> 131072 */
#define OFF_W1PH   31475712u   /* f16 256*384    ->  49152 */
#define OFF_MAP    31524864u   /* int 24960+1248     26208 */
#define WS_FLOATS  (31524864u + 26208u)   /* 126.2 MB < 127.57 known-good */

// ---------------------------------------------------------------------------
// prep: embed (fp32+f16) | all weight f16 conversions | maps + ctx zero.
// Region sizes: 327680 | 1081344 | 25088  -> grid 5602 * 256.
// ---------------------------------------------------------------------------
__global__ __launch_bounds__(256) void prep_kernel(
    const int* __restrict__ tokens, const float* __restrict__ etab,
    const float* __restrict__ pos,
    const float* __restrict__ ipw, const float* __restrict__ opw,
    const float* __restrict__ l1w, const float* __restrict__ l2w,
    const float* __restrict__ fw1,
    float* __restrict__ emb, f16* __restrict__ embh,
    f16* __restrict__ wqkvh, f16* __restrict__ wq1h, f16* __restrict__ kvwh,
    f16* __restrict__ woh, f16* __restrict__ l1wh, f16* __restrict__ l2wh,
    f16* __restrict__ w1ph,
    int* __restrict__ map1, int* __restrict__ map2, float* __restrict__ ctx)
{
    int i = blockIdx.x * 256 + threadIdx.x;
    if (i < 327680) {                       // embed
        int r = i >> 8, j = i & 255;
        int p = r % TS;
        float v = etab[(size_t)tokens[r] * DM + j] + pos[p * DM + j];
        emb[i] = v; embh[i] = (f16)v;
        return;
    }
    i -= 327680;
    if (i < 196608) { wqkvh[i] = (f16)ipw[i]; return; }                    // L0 qkv W
    i -= 196608;
    if (i < 65536)  { wq1h[i] = (f16)ipw[196608 + i]; return; }            // L1 q W
    i -= 65536;
    if (i < 131072) { kvwh[i] = (f16)ipw[196608 + 65536 + i]; return; }    // L1 kv W
    i -= 131072;
    if (i < 65536)  { woh[i] = (f16)opw[i]; return; }                      // L0 out W
    i -= 65536;
    if (i < 262144) { l1wh[i] = (f16)l1w[i]; return; }                     // L0 lin1 W
    i -= 262144;
    if (i < 262144) { l2wh[i] = (f16)l2w[i]; return; }                     // L0 lin2 W
    i -= 262144;
    if (i < 98304) {                                                       // w1p (strided)
        int r = i / 384, c = i - r * 384;
        w1ph[i] = (f16)fw1[r * 640 + c];
        return;
    }
    i -= 98304;
    // maps region (25088)
    if (i < BB * DM) ctx[i] = 0.f;
    if (i < NQ2) {
        int t = i >> 5, b = i & 31;
        map2[i] = ((t * (t + 1)) / 2 + t) * 32 + b;
    }
    if (i < NTOK) {
        int q = i >> 5, b = i & 31;
        int t = 0;
        while (((t + 1) * (t + 2)) / 2 <= q) ++t;
        int p = q - (t * (t + 1)) / 2;
        map1[i] = b * TS + p;
    }
}

// ---------------------------------------------------------------------------
// fp32 GEMM (small M, M-tail OK) — layer-1 small GEMMs (M=1248).
// ---------------------------------------------------------------------------
template <bool RELU>
__global__ __launch_bounds__(256) void gemm_nt(
    const float* __restrict__ A, int lda,
    const float* __restrict__ B, int ldb,
    const float* __restrict__ bias,
    float* __restrict__ C, int ldc, int M, int N, int K)
{
    __shared__ __align__(16) float As[16][68];
    __shared__ __align__(16) float Bs[16][68];
    int m0 = blockIdx.y << 6, n0 = blockIdx.x << 6;
    int tid = threadIdx.x;
    int tx = tid & 15, ty = tid >> 4;
    int lm = tid >> 2, lk = (tid & 3) << 2;
    float acc[4][4] = {{0.f}};

    for (int k0 = 0; k0 < K; k0 += 16) {
        float4 av;
        int gm = m0 + lm;
        if (gm < M) av = *(const float4*)(A + (size_t)gm * lda + k0 + lk);
        else        av = make_float4(0.f, 0.f, 0.f, 0.f);
        float4 bv = *(const float4*)(B + (size_t)(n0 + lm) * ldb + k0 + lk);
        As[lk + 0][lm] = av.x; As[lk + 1][lm] = av.y;
        As[lk + 2][lm] = av.z; As[lk + 3][lm] = av.w;
        Bs[lk + 0][lm] = bv.x; Bs[lk + 1][lm] = bv.y;
        Bs[lk + 2][lm] = bv.z; Bs[lk + 3][lm] = bv.w;
        __syncthreads();
#pragma unroll
        for (int kk = 0; kk < 16; ++kk) {
            float4 a = *(const float4*)&As[kk][ty << 2];
            float4 b = *(const float4*)&Bs[kk][tx << 2];
            acc[0][0] += a.x * b.x; acc[0][1] += a.x * b.y; acc[0][2] += a.x * b.z; acc[0][3] += a.x * b.w;
            acc[1][0] += a.y * b.x; acc[1][1] += a.y * b.y; acc[1][2] += a.y * b.z; acc[1][3] += a.y * b.w;
            acc[2][0] += a.z * b.x; acc[2][1] += a.z * b.y; acc[2][2] += a.z * b.z; acc[2][3] += a.z * b.w;
            acc[3][0] += a.w * b.x; acc[3][1] += a.w * b.y; acc[3][2] += a.w * b.z; acc[3][3] += a.w * b.w;
        }
        __syncthreads();
    }
#pragma unroll
    for (int i = 0; i < 4; ++i) {
        int gm = m0 + (ty << 2) + i;
        if (gm >= M) continue;
#pragma unroll
        for (int jj = 0; jj < 4; ++jj) {
            int gn = n0 + (tx << 2) + jj;
            float v = acc[i][jj];
            if (bias) v += bias[gn];
            if (RELU) v = fmaxf(v, 0.f);
            C[(size_t)gm * ldc + gn] = v;
        }
    }
}

// ---------------------------------------------------------------------------
// MFMA GEMM, BM x 128 tile (BM = 64 or 128), 4 waves.
// A = f16 (async global_load_lds, 16B/lane) or float (reg-convert staging).
// B = f16 always (async). fp32 accumulate. M%BM==0, N%128==0, K%64==0.
// LDS fragment-ordered: frag base is wave-uniform; lane data at base+lane*16
// — exactly global_load_lds's write pattern [m97/m104].
// ---------------------------------------------------------------------------
__device__ __forceinline__ half8 load_frag8(const float* p) {
    float4 a0 = *(const float4*)p;
    float4 a1 = *(const float4*)(p + 4);
    half8 h;
    h[0] = (f16)a0.x; h[1] = (f16)a0.y; h[2] = (f16)a0.z; h[3] = (f16)a0.w;
    h[4] = (f16)a1.x; h[5] = (f16)a1.y; h[6] = (f16)a1.z; h[7] = (f16)a1.w;
    return h;
}

__device__ __forceinline__ void stage16(const f16* g, f16* lbase_wave_uniform) {
    __builtin_amdgcn_global_load_lds(
        (const __attribute__((address_space(1))) void*)g,
        (__attribute__((address_space(3))) void*)lbase_wave_uniform, 16, 0, 0);
}

template <int BM, typename TA, bool RELU, bool OUTF16>
__global__ __launch_bounds__(256) void gemm_x(
    const TA* __restrict__ A, int lda,
    const f16* __restrict__ B, int ldb,
    const float* __restrict__ bias,
    void* __restrict__ Cv, int ldc, int K)
{
    constexpr int AF  = BM / 8;       // # A frags
    constexpr int TF  = AF + 16;      // total frags (A + B)
    constexpr int MRE = BM / 32;      // acc rows per wave
    __shared__ __align__(16) f16 lds[TF * 512];
    int tid = threadIdx.x;
    int w = tid >> 6, l = tid & 63;
    int m0 = blockIdx.y * BM, n0 = blockIdx.x << 7;
    int lrow = l & 15;
    int lk8  = (l >> 4) << 3;
    int wm = w >> 1, wn = w & 1;

    f32x4 acc[MRE][4] = {};

    for (int k0 = 0; k0 < K; k0 += 64) {
#pragma unroll
        for (int j = 0; j < TF / 4; ++j) {
            int f = w * (TF / 4) + j;                 // wave-uniform frag id
            if (f < AF) {
                int mi = f >> 1, kc = f & 1;
                const TA* ga = A + (size_t)(m0 + (mi << 4) + lrow) * lda + k0 + (kc << 5) + lk8;
                if constexpr (__is_same(TA, f16)) {
                    stage16(ga, &lds[f << 9]);
                } else {
                    *(half8*)&lds[(f << 9) + (l << 3)] = load_frag8(ga);
                }
            } else {
                int fb = f - AF;
                int nj = fb >> 1, kc = fb & 1;
                const f16* gb = B + (size_t)(n0 + (nj << 4) + lrow) * ldb + k0 + (kc << 5) + lk8;
                stage16(gb, &lds[f << 9]);
            }
        }
        __syncthreads();                               // drains vmcnt+lgkmcnt
#pragma unroll
        for (int kc = 0; kc < 2; ++kc) {
            half8 af[MRE], bfr[4];
#pragma unroll
            for (int i = 0; i < MRE; ++i)
                af[i] = *(half8*)&lds[((((wm * MRE + i) << 1) | kc) << 9) + (l << 3)];
#pragma unroll
            for (int j2 = 0; j2 < 4; ++j2)
                bfr[j2] = *(half8*)&lds[((AF + ((((wn << 2) | j2) << 1) | kc)) << 9) + (l << 3)];
#pragma unroll
            for (int i = 0; i < MRE; ++i)
#pragma unroll
                for (int j2 = 0; j2 < 4; ++j2)
                    acc[i][j2] = __builtin_amdgcn_mfma_f32_16x16x32_f16(
                        af[i], bfr[j2], acc[i][j2], 0, 0, 0);
        }
        __syncthreads();
    }

    // epilogue: D col = lane&15, row = (lane>>4)*4 + reg   [m89/m91 verified]
    int colq = l & 15, rowq = (l >> 4) << 2;
#pragma unroll
    for (int i = 0; i < MRE; ++i) {
        int gmb = m0 + (wm * MRE + i) * 16 + rowq;
#pragma unroll
        for (int j2 = 0; j2 < 4; ++j2) {
            int gn = n0 + ((wn << 2) | j2) * 16 + colq;
            float bv = bias ? bias[gn] : 0.f;
#pragma unroll
            for (int r = 0; r < 4; ++r) {
                float v = acc[i][j2][r] + bv;
                if (RELU) v = fmaxf(v, 0.f);
                if (OUTF16)
                    ((f16*)Cv)[(size_t)(gmb + r) * ldc + gn] = (f16)v;
                else
                    ((float*)Cv)[(size_t)(gmb + r) * ldc + gn] = v;
            }
        }
    }
}

// ---------------------------------------------------------------------------
// LayerNorm: one WAVE per row, float4 lanes, pure shuffle reductions.
// ---------------------------------------------------------------------------
__global__ __launch_bounds__(256) void ln_kernel(
    float* __restrict__ X, const float* __restrict__ res,
    const int* __restrict__ map, const float* __restrict__ g,
    const float* __restrict__ beta, int nrows)
{
    int r = blockIdx.x * 4 + (threadIdx.x >> 6);
    if (r >= nrows) return;
    int l = threadIdx.x & 63;
    float* xp = X + (size_t)r * DM + l * 4;
    float4 v = *(float4*)xp;
    if (res) {
        int rr = map ? map[r] : r;
        float4 rv = *(const float4*)(res + (size_t)rr * DM + l * 4);
        v.x += rv.x; v.y += rv.y; v.z += rv.z; v.w += rv.w;
    }
    float s = v.x + v.y + v.z + v.w;
#pragma unroll
    for (int o = 32; o; o >>= 1) s += __shfl_xor(s, o);
    float mean = s * (1.f / 256.f);
    float dx = v.x - mean, dy = v.y - mean, dz = v.z - mean, dw = v.w - mean;
    float s2 = dx * dx + dy * dy + dz * dz + dw * dw;
#pragma unroll
    for (int o = 32; o; o >>= 1) s2 += __shfl_xor(s2, o);
    float rstd = 1.f / sqrtf(s2 * (1.f / 256.f) + 1e-5f);
    float4 gv = *(const float4*)(g + l * 4);
    float4 bv = *(const float4*)(beta + l * 4);
    float4 ov;
    ov.x = dx * rstd * gv.x + bv.x;
    ov.y = dy * rstd * gv.y + bv.y;
    ov.z = dz * rstd * gv.z + bv.z;
    ov.w = dw * rstd * gv.w + bv.w;
    *(float4*)xp = ov;
}

// ---------------------------------------------------------------------------
// Layer-0 attention, online-softmax prefix scan (fp32 in, f16 packed out).
// ---------------------------------------------------------------------------
__global__ __launch_bounds__(256) void attn0_kernel(
    const float* __restrict__ qkv, f16* __restrict__ ao)
{
    int bp = blockIdx.x;               // b*39 + p
    int b = bp / 39, p = bp % 39;
    int tid = threadIdx.x;
    int h = tid >> 6, l = tid & 63;

    float qv = qkv[(size_t)(b * TS + p) * 768 + h * 64 + l];

    int krow = (l < 39) ? l : 38;
    const float* Kr = qkv + (size_t)(b * TS + krow) * 768 + 256 + h * 64;
    float acc = 0.f;
#pragma unroll
    for (int d4 = 0; d4 < 16; ++d4) {
        float4 k4 = *(const float4*)(Kr + d4 * 4);
        acc += __shfl(qv, d4 * 4 + 0) * k4.x;
        acc += __shfl(qv, d4 * 4 + 1) * k4.y;
        acc += __shfl(qv, d4 * 4 + 2) * k4.z;
        acc += __shfl(qv, d4 * 4 + 3) * k4.w;
    }
    float s = acc * 0.125f;

    float m = -1e30f, lsum = 0.f, o = 0.f;
    for (int t = p; t < TM1; ++t) {
        float st = __shfl(s, t);
        float mnew = fmaxf(m, st);
        float c = __expf(m - mnew);
        float e = __expf(st - mnew);
        lsum = lsum * c + e;
        float vv = qkv[(size_t)(b * TS + t) * 768 + 512 + h * 64 + l];
        o = o * c + e * vv;
        m = mnew;
        int row = ((t * (t + 1)) >> 1) + p;
        ao[((size_t)row * 32 + b) * DM + h * 64 + l] = (f16)(o / lsum);
    }
}

// ---------------------------------------------------------------------------
// Layer-1 attention. Block per (t,b): 4 waves = 4 heads; q = Wq(f16)@h1 row;
// scores lane=key over f16 K; PV lane=dim over f16 V.
// ---------------------------------------------------------------------------
__global__ __launch_bounds__(256) void attn1_kernel(
    const float* __restrict__ h1, const f16* __restrict__ kv1,
    const f16* __restrict__ Wq, const float* __restrict__ bq,
    float* __restrict__ ao1)
{
    int tb = blockIdx.x;
    int t = tb >> 5, b = tb & 31;
    int tid = threadIdx.x;
    int h = tid >> 6, l = tid & 63;
    int tri = (t * (t + 1)) >> 1;
    __shared__ float h1r[DM];
    h1r[tid] = h1[((size_t)(tri + t) * 32 + b) * DM + tid];
    __syncthreads();

    // q for dim l of head h (f16 weights, fp32 accumulate)
    float q = bq[h * 64 + l];
    const half8* w8 = (const half8*)(Wq + (size_t)(h * 64 + l) * DM);
#pragma unroll 8
    for (int c = 0; c < 32; ++c) {
        half8 ww = w8[c];
#pragma unroll
        for (int j = 0; j < 8; ++j)
            q += (float)ww[j] * h1r[c * 8 + j];
    }

    // score: lane l = key row (clamped)
    int kr = (l <= t) ? l : t;
    const f16* Kp = kv1 + ((size_t)(tri + kr) * 32 + b) * 512 + h * 64;
    float sc = 0.f;
#pragma unroll
    for (int c = 0; c < 8; ++c) {
        half8 k8 = *(const half8*)(Kp + c * 8);
#pragma unroll
        for (int j = 0; j < 8; ++j)
            sc += __shfl(q, c * 8 + j) * (float)k8[j];
    }
    sc = (l <= t) ? sc * 0.125f : -1e30f;
    float m = sc;
#pragma unroll
    for (int o = 32; o; o >>= 1) m = fmaxf(m, __shfl_xor(m, o));
    float e = (l <= t) ? __expf(sc - m) : 0.f;
    float ss = e;
#pragma unroll
    for (int o = 32; o; o >>= 1) ss += __shfl_xor(ss, o);
    float a = e / ss;

    // PV: lane l = dim
    float o = 0.f;
    for (int k = 0; k <= t; ++k) {
        float ak = __shfl(a, k);
        o += ak * (float)kv1[((size_t)(tri + k) * 32 + b) * 512 + 256 + h * 64 + l];
    }
    ao1[(size_t)tb * DM + h * 64 + l] = o;
}

// ---------------------------------------------------------------------------
// per (t,b): u = fus_w2^T @ cls_w[tok]; cpb = ctx@w1c^T + fus_b1;
//            s = fus_b2 . cls_w[tok] + cls_b[tok]
// ---------------------------------------------------------------------------
__global__ __launch_bounds__(256) void fuse_prep(
    const float* __restrict__ ctx, const int* __restrict__ tokens,
    const float* __restrict__ fw1, const float* __restrict__ fb1,
    const float* __restrict__ fw2, const float* __restrict__ fb2,
    const float* __restrict__ clsw, const float* __restrict__ clsb,
    float* __restrict__ cpb, float* __restrict__ u, float* __restrict__ sv)
{
    int tb = blockIdx.x;               // t*32+b
    int t = tb >> 5, b = tb & 31;
    int j = threadIdx.x;
    __shared__ float cw[DM];
    __shared__ float cr[DM];
    __shared__ float red[4];
    int tok = tokens[b * TS + t];
    cw[j] = clsw[(size_t)tok * DM + j];
    cr[j] = ctx[(size_t)tb * DM + j];
    __syncthreads();
    float uj = 0.f;
    for (int m = 0; m < DM; ++m) uj += fw2[m * DM + j] * cw[m];
    u[(size_t)tb * DM + j] = uj;
    float c = fb1[j];
    const float4* w1c = (const float4*)(fw1 + (size_t)j * (DINO + DM) + DINO);
    for (int d4 = 0; d4 < 64; ++d4) {
        float4 wv = w1c[d4];
        c += wv.x * cr[d4 * 4] + wv.y * cr[d4 * 4 + 1] +
             wv.z * cr[d4 * 4 + 2] + wv.w * cr[d4 * 4 + 3];
    }
    cpb[(size_t)tb * DM + j] = c;
    float s = fb2[j] * cw[j];
#pragma unroll
    for (int o = 32; o; o >>= 1) s += __shfl_xor(s, o);
    if ((j & 63) == 0) red[j >> 6] = s;
    __syncthreads();
    if (j == 0) sv[tb] = red[0] + red[1] + red[2] + red[3] + clsb[tok];
}

// ---------------------------------------------------------------------------
// Fast gelu: AS 7.1.26 erf, |err| <= 1.5e-7.
// ---------------------------------------------------------------------------
__device__ __forceinline__ float gelu_f(float x)
{
    float ax = fabsf(x);
    float z  = ax * 0.70710678118654752440f;
    float tt = __builtin_amdgcn_rcpf(1.f + 0.3275911f * z);
    float pl = ((((1.061405429f * tt - 1.453152027f) * tt + 1.421413741f) * tt
                 - 0.284496736f) * tt + 0.254829592f) * tt;
    float E  = 1.f - pl * __expf(-z * z);
    return 0.5f * x + 0.5f * ax * E;
}

// ---------------------------------------------------------------------------
// out[b,p,t] = sigmoid( sum_k gelu(pp+cpb)*u + s ). Block per (b,p);
// wave w: t = w, w+4, ...; lane l covers k = 4l..4l+3.
// ---------------------------------------------------------------------------
__global__ __launch_bounds__(256) void final_out(
    const f16* __restrict__ pp, const float* __restrict__ cpb,
    const float* __restrict__ u, const float* __restrict__ sv,
    float* __restrict__ out)
{
    int bp = blockIdx.x;               // b*256+p
    int b = bp >> 8;
    int tid = threadIdx.x;
    int w = tid >> 6, l = tid & 63;
    const f16* ppr = pp + (size_t)bp * DM + l * 4;
    float p0 = (float)ppr[0], p1 = (float)ppr[1];
    float p2 = (float)ppr[2], p3 = (float)ppr[3];
    for (int t = w; t < TS; t += 4) {
        int tb = t * 32 + b;
        float4 cp = *(const float4*)(cpb + (size_t)tb * DM + l * 4);
        float4 uu = *(const float4*)(u + (size_t)tb * DM + l * 4);
        float v = gelu_f(p0 + cp.x) * uu.x + gelu_f(p1 + cp.y) * uu.y +
                  gelu_f(p2 + cp.z) * uu.z + gelu_f(p3 + cp.w) * uu.w;
#pragma unroll
        for (int off = 32; off; off >>= 1) v += __shfl_xor(v, off);
        if (l == 0) out[(size_t)bp * TS + t] = 1.f / (1.f + __expf(-(v + sv[tb])));
    }
}

// ---------------------------------------------------------------------------
// Launcher
// ---------------------------------------------------------------------------
extern "C" void kernel_launch(void* const* d_in, const int* in_sizes, int n_in,
                              void* d_out, int out_size, void* d_ws, size_t ws_size,
                              hipStream_t stream)
{
    (void)in_sizes; (void)n_in; (void)out_size;
    const float* patches   = (const float*)d_in[0];
    const int*   tokens    = (const int*)  d_in[1];
    const float* embedding = (const float*)d_in[2];
    const float* pos_emb   = (const float*)d_in[3];
    const float* in_proj_w = (const float*)d_in[4];
    const float* in_proj_b = (const float*)d_in[5];
    const float* out_proj_w= (const float*)d_in[6];
    const float* out_proj_b= (const float*)d_in[7];
    const float* lin1_w    = (const float*)d_in[8];
    const float* lin1_b    = (const float*)d_in[9];
    const float* lin2_w    = (const float*)d_in[10];
    const float* lin2_b    = (const float*)d_in[11];
    const float* ln1_g     = (const float*)d_in[12];
    const float* ln1_b     = (const float*)d_in[13];
    const float* ln2_g     = (const float*)d_in[14];
    const float* ln2_b     = (const float*)d_in[15];
    const float* fus_w1    = (const float*)d_in[16];
    const float* fus_b1    = (const float*)d_in[17];
    const float* fus_w2    = (const float*)d_in[18];
    const float* fus_b2    = (const float*)d_in[19];
    const float* cls_w     = (const float*)d_in[20];
    const float* cls_b     = (const float*)d_in[21];

    if (ws_size < (size_t)WS_FLOATS * 4) return;

    float* ws   = (float*)d_ws;
    float* emb  = ws + OFF_EMB;
    f16*   embh = (f16*)(ws + OFF_EMBH);
    float* qkv0 = ws + OFF_QKV0;
    float* x1   = ws + OFF_X1;
    float* h1   = ws + OFF_H1;
    float* big  = ws + OFF_BIG;
    f16*   ao0h = (f16*)big;          // 24960*256 f16
    f16*   ff1h = (f16*)big;          // 24960*1024 f16 (51.1 MB, exact)
    f16*   kv1h = (f16*)big;          // 24960*512 f16
    float* ao1  = ws + OFF_AO1;
    float* x2   = ws + OFF_X2;
    float* ff2  = ws + OFF_FF2;
    float* ctx  = ws + OFF_CTX;
    f16*   pph  = (f16*)(ws + OFF_PPH);
    float* cpb  = ws + OFF_CPB;
    float* u    = ws + OFF_U;
    float* svec = ws + OFF_S;
    f16*   wqkvh= (f16*)(ws + OFF_WQKVH);
    f16*   wq1h = (f16*)(ws + OFF_WQ1H);
    f16*   kvwh = (f16*)(ws + OFF_KVWH);
    f16*   woh  = (f16*)(ws + OFF_WOH);
    f16*   l1wh = (f16*)(ws + OFF_L1WH);
    f16*   l2wh = (f16*)(ws + OFF_L2WH);
    f16*   w1ph = (f16*)(ws + OFF_W1PH);
    int*   map1 = (int*)(ws + OFF_MAP);
    int*   map2 = map1 + NTOK;

    prep_kernel<<<5602, 256, 0, stream>>>(
        tokens, embedding, pos_emb, in_proj_w, out_proj_w, lin1_w, lin2_w, fus_w1,
        emb, embh, wqkvh, wq1h, kvwh, woh, l1wh, l2wh, w1ph, map1, map2, ctx);

    // ---- Layer 0 ----
    // QKV: M=1280(20x64), N=768(6), K=256
    gemm_x<64, f16, false, false><<<dim3(6, 20), 256, 0, stream>>>(
        embh, DM, wqkvh, DM, in_proj_b, qkv0, 768, DM);
    attn0_kernel<<<NQ2, 256, 0, stream>>>(qkv0, ao0h);
    // out-proj: M=24960(390x64), N=256(2), K=256
    gemm_x<64, f16, false, false><<<dim3(2, 390), 256, 0, stream>>>(
        ao0h, DM, woh, DM, out_proj_b, x1, DM, DM);
    ln_kernel<<<6240, 256, 0, stream>>>(x1, emb, map1, ln1_g, ln1_b, NTOK);
    // lin1: M=24960(195x128), N=1024(8), K=256 (A fp32 reg-convert)
    gemm_x<128, float, true, true><<<dim3(8, 195), 256, 0, stream>>>(
        x1, DM, l1wh, DM, lin1_b, ff1h, DFF, DM);
    // lin2: M=24960(390x64), N=256(2), K=1024 (A f16 async)
    gemm_x<64, f16, false, false><<<dim3(2, 390), 256, 0, stream>>>(
        ff1h, DFF, l2wh, DFF, lin2_b, h1, DM, DFF);
    ln_kernel<<<6240, 256, 0, stream>>>(h1, x1, nullptr, ln2_g, ln2_b, NTOK);

    // ---- Layer 1 ----
    // K/V: M=24960(195x128), N=512(4), K=256 -> f16 packed (aliases big)
    gemm_x<128, float, false, true><<<dim3(4, 195), 256, 0, stream>>>(
        h1, DM, kvwh, DM, in_proj_b + 768 + 256, kv1h, 512, DM);
    attn1_kernel<<<NQ2, 256, 0, stream>>>(
        h1, kv1h, wq1h, in_proj_b + 768, ao1);
    gemm_nt<false><<<dim3(4, 20), 256, 0, stream>>>(
        ao1, DM, out_proj_w + DM * DM, DM, out_proj_b + DM, x2, DM, NQ2, DM, DM);
    ln_kernel<<<312, 256, 0, stream>>>(x2, h1, map2, ln1_g + DM, ln1_b + DM, NQ2);
    gemm_nt<true><<<dim3(16, 20), 256, 0, stream>>>(
        x2, DM, lin1_w + DFF * DM, DM, lin1_b + DFF, ff2, DFF, NQ2, DFF, DM);
    gemm_nt<false><<<dim3(4, 20), 256, 0, stream>>>(
        ff2, DFF, lin2_w + DM * DFF, DFF, lin2_b + DM, ctx + BB * DM, DM, NQ2, DM, DFF);
    ln_kernel<<<312, 256, 0, stream>>>(ctx + BB * DM, x2, nullptr, ln2_g + DM, ln2_b + DM, NQ2);

    // ---- Fusion head ----
    // pp: M=8192(128x64), N=256(2), K=384 (A fp32 reg-convert)
    gemm_x<64, float, false, true><<<dim3(2, 128), 256, 0, stream>>>(
        patches, DINO, w1ph, DINO, nullptr, pph, DM, DINO);
    fuse_prep<<<TS * BB, 256, 0, stream>>>(
        ctx, tokens, fus_w1, fus_b1, fus_w2, fus_b2, cls_w, cls_b, cpb, u, svec);
    final_out<<<BB * NPATCH, 256, 0, stream>>>(pph, cpb, u, svec, (float*)d_out);
}

// Round 8
// 600.873 us; speedup vs baseline: 1.0377x; 1.0377x over previous
//
#include <hip/hip_runtime.h>
#include <math.h>

// ---------------------------------------------------------------------------
// Problem constants
// ---------------------------------------------------------------------------
#define DM    256     // D_MODEL
#define NH    4
#define HD    64
#define TS    40
#define TM1   39
#define BB    32
#define DFF   1024
#define DINO  384
#define NPATCH 256
#define VOCAB 4096

#define NTOK  24960   // 780*32 packed (t, p<=t, b) tokens
#define NQ2   1248    // 39*32

typedef _Float16 f16;
typedef __attribute__((ext_vector_type(8))) _Float16 half8;  // MFMA A/B frag
typedef __attribute__((ext_vector_type(4))) _Float16 half4;
typedef __attribute__((ext_vector_type(4))) float f32x4;

// ---------------------------------------------------------------------------
// Workspace layout (float offsets). Residual/LN chain fp32 (round-3 lesson);
// f16 copies only where the consumer re-rounds anyway (GEMM-A, KV, pp).
// ff1 is never materialized (fused FF) -> big region only ao0h/kv1h.
// ---------------------------------------------------------------------------
#define OFF_EMB    0u          /* f32 1280*256   327680 */
#define OFF_EMBH   327680u     /* f16 1280*256   163840 */
#define OFF_QKV0   491520u     /* f32 1280*768   983040 */
#define OFF_X1     1474560u    /* f32 24960*256  6389760 */
#define OFF_X1H    7864320u    /* f16 24960*256  3194880 */
#define OFF_H1     11059200u   /* f32 24960*256  6389760 */
#define OFF_H1H    17448960u   /* f16 24960*256  3194880 */
#define OFF_BIG    20643840u   /* 6389760: ao0h (f16 24960*256) then kv1h (f16 24960*512) */
#define OFF_AO1    27033600u   /* f32 1248*256   319488 */
#define OFF_X2     27353088u   /* f32 1248*256   319488 */
#define OFF_FF2    27672576u   /* f32 1248*1024  1277952 */
#define OFF_CTX    28950528u   /* f32 1280*256   327680 */
#define OFF_PPH    29278208u   /* f16 8192*256   1048576 */
#define OFF_CPB    30326784u   /* f32 1280*256   327680 */
#define OFF_U      30654464u   /* f32 1280*256   327680 */
#define OFF_S      30982144u   /* f32 1280(+pad) 2048 */
#define OFF_WQKVH  30984192u   /* f16 768*256    ->  98304 */
#define OFF_WQ1H   31082496u   /* f16 256*256    ->  32768 */
#define OFF_KVWH   31115264u   /* f16 512*256    ->  65536 */
#define OFF_WOH    31180800u   /* f16 256*256    ->  32768 */
#define OFF_L1WH   31213568u   /* f16 1024*256   -> 131072 */
#define OFF_L2WH   31344640u   /* f16 256*1024   -> 131072 */
#define OFF_W1PH   31475712u   /* f16 256*384    ->  49152 */
#define OFF_MAP    31524864u   /* int 24960+1248     26208 */
#define WS_FLOATS  (31524864u + 26208u)   /* 126.2 MB */

// ---------------------------------------------------------------------------
// prep: embed (fp32+f16) | weight f16 conversions | maps + ctx zero.
// ---------------------------------------------------------------------------
__global__ __launch_bounds__(256) void prep_kernel(
    const int* __restrict__ tokens, const float* __restrict__ etab,
    const float* __restrict__ pos,
    const float* __restrict__ ipw, const float* __restrict__ opw,
    const float* __restrict__ l1w, const float* __restrict__ l2w,
    const float* __restrict__ fw1,
    float* __restrict__ emb, f16* __restrict__ embh,
    f16* __restrict__ wqkvh, f16* __restrict__ wq1h, f16* __restrict__ kvwh,
    f16* __restrict__ woh, f16* __restrict__ l1wh, f16* __restrict__ l2wh,
    f16* __restrict__ w1ph,
    int* __restrict__ map1, int* __restrict__ map2, float* __restrict__ ctx)
{
    int i = blockIdx.x * 256 + threadIdx.x;
    if (i < 327680) {                       // embed
        int r = i >> 8, j = i & 255;
        int p = r % TS;
        float v = etab[(size_t)tokens[r] * DM + j] + pos[p * DM + j];
        emb[i] = v; embh[i] = (f16)v;
        return;
    }
    i -= 327680;
    if (i < 196608) { wqkvh[i] = (f16)ipw[i]; return; }                    // L0 qkv W
    i -= 196608;
    if (i < 65536)  { wq1h[i] = (f16)ipw[196608 + i]; return; }            // L1 q W
    i -= 65536;
    if (i < 131072) { kvwh[i] = (f16)ipw[196608 + 65536 + i]; return; }    // L1 kv W
    i -= 131072;
    if (i < 65536)  { woh[i] = (f16)opw[i]; return; }                      // L0 out W
    i -= 65536;
    if (i < 262144) { l1wh[i] = (f16)l1w[i]; return; }                     // L0 lin1 W
    i -= 262144;
    if (i < 262144) { l2wh[i] = (f16)l2w[i]; return; }                     // L0 lin2 W
    i -= 262144;
    if (i < 98304) {                                                       // w1p (strided)
        int r = i / 384, c = i - r * 384;
        w1ph[i] = (f16)fw1[r * 640 + c];
        return;
    }
    i -= 98304;
    if (i < BB * DM) ctx[i] = 0.f;
    if (i < NQ2) {
        int t = i >> 5, b = i & 31;
        map2[i] = ((t * (t + 1)) / 2 + t) * 32 + b;
    }
    if (i < NTOK) {
        int q = i >> 5, b = i & 31;
        int t = 0;
        while (((t + 1) * (t + 2)) / 2 <= q) ++t;
        int p = q - (t * (t + 1)) / 2;
        map1[i] = b * TS + p;
    }
}

// ---------------------------------------------------------------------------
// async 16B/lane global->LDS stage (wave-uniform LDS base) [m97/m104]
// ---------------------------------------------------------------------------
__device__ __forceinline__ void stage16(const f16* g, f16* lbase_wave_uniform) {
    __builtin_amdgcn_global_load_lds(
        (const __attribute__((address_space(1))) void*)g,
        (__attribute__((address_space(3))) void*)lbase_wave_uniform, 16, 0, 0);
}

__device__ __forceinline__ half8 load_frag8(const f16* p) { return *(const half8*)p; }
__device__ __forceinline__ half8 load_frag8(const float* p) {
    float4 a0 = *(const float4*)p;
    float4 a1 = *(const float4*)(p + 4);
    half8 h;
    h[0] = (f16)a0.x; h[1] = (f16)a0.y; h[2] = (f16)a0.z; h[3] = (f16)a0.w;
    h[4] = (f16)a1.x; h[5] = (f16)a1.y; h[6] = (f16)a1.z; h[7] = (f16)a1.w;
    return h;
}

// ---------------------------------------------------------------------------
// Standard MFMA GEMM (QKV, pp): BM x 128 tile, 4 waves, balanced frag
// mapping f = j*4 + w (each wave stages equal A and B work).
// ---------------------------------------------------------------------------
template <int BM, typename TA, bool RELU, bool OUTF16>
__global__ __launch_bounds__(256) void gemm_x(
    const TA* __restrict__ A, int lda,
    const f16* __restrict__ B, int ldb,
    const float* __restrict__ bias,
    void* __restrict__ Cv, int ldc, int K)
{
    constexpr int AF  = BM / 8;       // # A frags
    constexpr int TF  = AF + 16;      // total frags
    constexpr int MRE = BM / 32;      // acc rows per wave
    __shared__ __align__(16) f16 lds[TF * 512];
    int tid = threadIdx.x;
    int w = tid >> 6, l = tid & 63;
    int m0 = blockIdx.y * BM, n0 = blockIdx.x << 7;
    int lrow = l & 15;
    int lk8  = (l >> 4) << 3;
    int wm = w >> 1, wn = w & 1;

    f32x4 acc[MRE][4] = {};

    for (int k0 = 0; k0 < K; k0 += 64) {
#pragma unroll
        for (int j = 0; j < TF / 4; ++j) {
            int f = (j << 2) | w;                      // balanced across waves
            if (f < AF) {
                int mi = f >> 1, kc = f & 1;
                const TA* ga = A + (size_t)(m0 + (mi << 4) + lrow) * lda + k0 + (kc << 5) + lk8;
                if constexpr (__is_same(TA, f16)) {
                    stage16(ga, &lds[f << 9]);
                } else {
                    *(half8*)&lds[(f << 9) + (l << 3)] = load_frag8(ga);
                }
            } else {
                int fb = f - AF;
                int nj = fb >> 1, kc = fb & 1;
                const f16* gb = B + (size_t)(n0 + (nj << 4) + lrow) * ldb + k0 + (kc << 5) + lk8;
                stage16(gb, &lds[f << 9]);
            }
        }
        __syncthreads();
#pragma unroll
        for (int kc = 0; kc < 2; ++kc) {
            half8 af[MRE], bfr[4];
#pragma unroll
            for (int i = 0; i < MRE; ++i)
                af[i] = *(half8*)&lds[((((wm * MRE + i) << 1) | kc) << 9) + (l << 3)];
#pragma unroll
            for (int j2 = 0; j2 < 4; ++j2)
                bfr[j2] = *(half8*)&lds[((AF + ((((wn << 2) | j2) << 1) | kc)) << 9) + (l << 3)];
#pragma unroll
            for (int i = 0; i < MRE; ++i)
#pragma unroll
                for (int j2 = 0; j2 < 4; ++j2)
                    acc[i][j2] = __builtin_amdgcn_mfma_f32_16x16x32_f16(
                        af[i], bfr[j2], acc[i][j2], 0, 0, 0);
        }
        __syncthreads();
    }

    int colq = l & 15, rowq = (l >> 4) << 2;           // C/D map [m89/m91]
#pragma unroll
    for (int i = 0; i < MRE; ++i) {
        int gmb = m0 + (wm * MRE + i) * 16 + rowq;
#pragma unroll
        for (int j2 = 0; j2 < 4; ++j2) {
            int gn = n0 + ((wn << 2) | j2) * 16 + colq;
            float bv = bias ? bias[gn] : 0.f;
#pragma unroll
            for (int r = 0; r < 4; ++r) {
                float v = acc[i][j2][r] + bv;
                if (RELU) v = fmaxf(v, 0.f);
                if (OUTF16)
                    ((f16*)Cv)[(size_t)(gmb + r) * ldc + gn] = (f16)v;
                else
                    ((float*)Cv)[(size_t)(gmb + r) * ldc + gn] = v;
            }
        }
    }
}

// ---------------------------------------------------------------------------
// A-resident MFMA GEMM (out-proj, kv): BM=64, full 64xK f16 A-tile staged
// async into LDS ONCE; n-chunk loop with B frags loaded direct global->reg
// (B <= 512 KB, L2-resident). No barriers in the main loop. A fetched once.
// ---------------------------------------------------------------------------
template <int K, int NCH, bool OUTF16>
__global__ __launch_bounds__(256) void gemm_ar(
    const f16* __restrict__ A,            // lda = K
    const f16* __restrict__ B,            // ldb = K
    const float* __restrict__ bias,
    void* __restrict__ Cv, int ldc)
{
    constexpr int KC = K / 32;            // 32-wide k chunks (8 for K=256)
    __shared__ __align__(16) f16 Asl[64 * K];   // 4*KC frags of 1 KB
    int tid = threadIdx.x;
    int w = tid >> 6, l = tid & 63;
    int m0 = blockIdx.x * 64;
    int lrow = l & 15, lk8 = (l >> 4) << 3;
    int wm = w >> 1, wn = w & 1;

    // stage all A frags (frag s = mi*KC + kc), balanced: f = j*4 + w
#pragma unroll
    for (int j = 0; j < KC; ++j) {
        int f = (j << 2) | w;
        int mi = f / KC, kc = f % KC;
        const f16* ga = A + (size_t)(m0 + mi * 16 + lrow) * K + kc * 32 + lk8;
        stage16(ga, &Asl[f << 9]);
    }
    __syncthreads();

#pragma unroll
    for (int n = 0; n < NCH; ++n) {
        int n0 = n << 7;
        f32x4 acc[2][4] = {};
#pragma unroll
        for (int kc = 0; kc < KC; ++kc) {
            half8 af[2], bfr[4];
#pragma unroll
            for (int i = 0; i < 2; ++i)
                af[i] = *(half8*)&Asl[(((wm * 2 + i) * KC + kc) << 9) + (l << 3)];
#pragma unroll
            for (int j2 = 0; j2 < 4; ++j2) {
                int nj = (wn << 2) | j2;
                bfr[j2] = *(const half8*)(B + (size_t)(n0 + nj * 16 + lrow) * K + kc * 32 + lk8);
            }
#pragma unroll
            for (int i = 0; i < 2; ++i)
#pragma unroll
                for (int j2 = 0; j2 < 4; ++j2)
                    acc[i][j2] = __builtin_amdgcn_mfma_f32_16x16x32_f16(
                        af[i], bfr[j2], acc[i][j2], 0, 0, 0);
        }
        int colq = l & 15, rowq = (l >> 4) << 2;
#pragma unroll
        for (int i = 0; i < 2; ++i) {
            int gmb = m0 + (wm * 2 + i) * 16 + rowq;
#pragma unroll
            for (int j2 = 0; j2 < 4; ++j2) {
                int gn = n0 + ((wn << 2) | j2) * 16 + colq;
                float bv = bias ? bias[gn] : 0.f;
#pragma unroll
                for (int r = 0; r < 4; ++r) {
                    float v = acc[i][j2][r] + bv;
                    if (OUTF16)
                        ((f16*)Cv)[(size_t)(gmb + r) * ldc + gn] = (f16)v;
                    else
                        ((float*)Cv)[(size_t)(gmb + r) * ldc + gn] = v;
                }
            }
        }
    }
}

// ---------------------------------------------------------------------------
// Fused FF: h1[64xDM] = relu(x1h_tile @ W1^T + b1) @ W2^T + b2, per 64-row
// block. x-tile LDS-resident; p-tile (64x128) round-trips through LDS
// (C-layout write -> A-layout read, m120-verified transform). ff1 never
// touches HBM. W1/W2 (512 KB each) stream from L2.
// ---------------------------------------------------------------------------
__global__ __launch_bounds__(256) void ff_fused(
    const f16* __restrict__ Xh,           // [M,256] f16
    const f16* __restrict__ W1,           // [1024,256] f16
    const float* __restrict__ b1,
    const f16* __restrict__ W2,           // [256,1024] f16
    const float* __restrict__ b2,
    float* __restrict__ H)                // [M,256] f32
{
    __shared__ __align__(16) f16 Asl[64 * 256];   // 32 KB x-tile (32 frags)
    __shared__ __align__(16) f16 P[64][136];      // 17 KB p-tile (+8 pad)
    int tid = threadIdx.x;
    int w = tid >> 6, l = tid & 63;
    int m0 = blockIdx.x * 64;
    int lrow = l & 15, lk8 = (l >> 4) << 3;
    int wm = w >> 1, wn = w & 1;
    int colq = l & 15, rowq = (l >> 4) << 2;

    // stage x-tile (frag s = mi*8 + kc)
#pragma unroll
    for (int j = 0; j < 8; ++j) {
        int f = (j << 2) | w;
        int mi = f >> 3, kc = f & 7;
        const f16* ga = Xh + (size_t)(m0 + mi * 16 + lrow) * 256 + kc * 32 + lk8;
        stage16(ga, &Asl[f << 9]);
    }
    __syncthreads();

    f32x4 accH[2][8] = {};

    for (int ff = 0; ff < 8; ++ff) {               // 128 ff-cols per chunk
        // phase 1: p = relu(x @ W1[ff-chunk]^T + b1)
        f32x4 accP[2][4] = {};
#pragma unroll
        for (int kc = 0; kc < 8; ++kc) {
            half8 af[2], bfr[4];
#pragma unroll
            for (int i = 0; i < 2; ++i)
                af[i] = *(half8*)&Asl[(((wm * 2 + i) * 8 + kc) << 9) + (l << 3)];
#pragma unroll
            for (int j2 = 0; j2 < 4; ++j2) {
                int gr = ff * 128 + ((wn << 2) | j2) * 16 + lrow;   // W1 row
                bfr[j2] = *(const half8*)(W1 + (size_t)gr * 256 + kc * 32 + lk8);
            }
#pragma unroll
            for (int i = 0; i < 2; ++i)
#pragma unroll
                for (int j2 = 0; j2 < 4; ++j2)
                    accP[i][j2] = __builtin_amdgcn_mfma_f32_16x16x32_f16(
                        af[i], bfr[j2], accP[i][j2], 0, 0, 0);
        }
        __syncthreads();                   // prior phase-2 reads of P done
#pragma unroll
        for (int i = 0; i < 2; ++i) {
            int pr = (wm * 2 + i) * 16 + rowq;
#pragma unroll
            for (int j2 = 0; j2 < 4; ++j2) {
                int pc = ((wn << 2) | j2) * 16 + colq;
                float bv = b1[ff * 128 + pc];
#pragma unroll
                for (int r = 0; r < 4; ++r)
                    P[pr + r][pc] = (f16)fmaxf(accP[i][j2][r] + bv, 0.f);
            }
        }
        __syncthreads();
        // phase 2: accH += P @ W2[:, ff-chunk]^T
#pragma unroll
        for (int kc = 0; kc < 4; ++kc) {
            half8 af[2], bfr[8];
#pragma unroll
            for (int i = 0; i < 2; ++i)
                af[i] = *(half8*)&P[(wm * 2 + i) * 16 + lrow][kc * 32 + lk8];
#pragma unroll
            for (int j2 = 0; j2 < 8; ++j2) {
                int gr = ((wn << 3) | j2) * 16 + lrow;              // W2 row (h1 col)
                bfr[j2] = *(const half8*)(W2 + (size_t)gr * 1024 + ff * 128 + kc * 32 + lk8);
            }
#pragma unroll
            for (int i = 0; i < 2; ++i)
#pragma unroll
                for (int j2 = 0; j2 < 8; ++j2)
                    accH[i][j2] = __builtin_amdgcn_mfma_f32_16x16x32_f16(
                        af[i], bfr[j2], accH[i][j2], 0, 0, 0);
        }
    }

    // epilogue: H (fp32)
#pragma unroll
    for (int i = 0; i < 2; ++i) {
        int gmb = m0 + (wm * 2 + i) * 16 + rowq;
#pragma unroll
        for (int j2 = 0; j2 < 8; ++j2) {
            int gn = ((wn << 3) | j2) * 16 + colq;
            float bv = b2[gn];
#pragma unroll
            for (int r = 0; r < 4; ++r)
                H[(size_t)(gmb + r) * DM + gn] = accH[i][j2][r] + bv;
        }
    }
}

// ---------------------------------------------------------------------------
// fp32 GEMM (small M) — layer-1 small GEMMs (M=1248).
// ---------------------------------------------------------------------------
template <bool RELU>
__global__ __launch_bounds__(256) void gemm_nt(
    const float* __restrict__ A, int lda,
    const float* __restrict__ B, int ldb,
    const float* __restrict__ bias,
    float* __restrict__ C, int ldc, int M, int N, int K)
{
    __shared__ __align__(16) float As[16][68];
    __shared__ __align__(16) float Bs[16][68];
    int m0 = blockIdx.y << 6, n0 = blockIdx.x << 6;
    int tid = threadIdx.x;
    int tx = tid & 15, ty = tid >> 4;
    int lm = tid >> 2, lk = (tid & 3) << 2;
    float acc[4][4] = {{0.f}};

    for (int k0 = 0; k0 < K; k0 += 16) {
        float4 av;
        int gm = m0 + lm;
        if (gm < M) av = *(const float4*)(A + (size_t)gm * lda + k0 + lk);
        else        av = make_float4(0.f, 0.f, 0.f, 0.f);
        float4 bv = *(const float4*)(B + (size_t)(n0 + lm) * ldb + k0 + lk);
        As[lk + 0][lm] = av.x; As[lk + 1][lm] = av.y;
        As[lk + 2][lm] = av.z; As[lk + 3][lm] = av.w;
        Bs[lk + 0][lm] = bv.x; Bs[lk + 1][lm] = bv.y;
        Bs[lk + 2][lm] = bv.z; Bs[lk + 3][lm] = bv.w;
        __syncthreads();
#pragma unroll
        for (int kk = 0; kk < 16; ++kk) {
            float4 a = *(const float4*)&As[kk][ty << 2];
            float4 b = *(const float4*)&Bs[kk][tx << 2];
            acc[0][0] += a.x * b.x; acc[0][1] += a.x * b.y; acc[0][2] += a.x * b.z; acc[0][3] += a.x * b.w;
            acc[1][0] += a.y * b.x; acc[1][1] += a.y * b.y; acc[1][2] += a.y * b.z; acc[1][3] += a.y * b.w;
            acc[2][0] += a.z * b.x; acc[2][1] += a.z * b.y; acc[2][2] += a.z * b.z; acc[2][3] += a.z * b.w;
            acc[3][0] += a.w * b.x; acc[3][1] += a.w * b.y; acc[3][2] += a.w * b.z; acc[3][3] += a.w * b.w;
        }
        __syncthreads();
    }
#pragma unroll
    for (int i = 0; i < 4; ++i) {
        int gm = m0 + (ty << 2) + i;
        if (gm >= M) continue;
#pragma unroll
        for (int jj = 0; jj < 4; ++jj) {
            int gn = n0 + (tx << 2) + jj;
            float v = acc[i][jj];
            if (bias) v += bias[gn];
            if (RELU) v = fmaxf(v, 0.f);
            C[(size_t)gm * ldc + gn] = v;
        }
    }
}

// ---------------------------------------------------------------------------
// LayerNorm: one WAVE per row, float4 lanes, shuffle reductions.
// Optional f16 dual-store (outh) for downstream GEMM-A consumption.
// ---------------------------------------------------------------------------
__global__ __launch_bounds__(256) void ln_kernel(
    float* __restrict__ X, const float* __restrict__ res,
    const int* __restrict__ map, const float* __restrict__ g,
    const float* __restrict__ beta, int nrows, f16* __restrict__ outh)
{
    int r = blockIdx.x * 4 + (threadIdx.x >> 6);
    if (r >= nrows) return;
    int l = threadIdx.x & 63;
    float* xp = X + (size_t)r * DM + l * 4;
    float4 v = *(float4*)xp;
    if (res) {
        int rr = map ? map[r] : r;
        float4 rv = *(const float4*)(res + (size_t)rr * DM + l * 4);
        v.x += rv.x; v.y += rv.y; v.z += rv.z; v.w += rv.w;
    }
    float s = v.x + v.y + v.z + v.w;
#pragma unroll
    for (int o = 32; o; o >>= 1) s += __shfl_xor(s, o);
    float mean = s * (1.f / 256.f);
    float dx = v.x - mean, dy = v.y - mean, dz = v.z - mean, dw = v.w - mean;
    float s2 = dx * dx + dy * dy + dz * dz + dw * dw;
#pragma unroll
    for (int o = 32; o; o >>= 1) s2 += __shfl_xor(s2, o);
    float rstd = 1.f / sqrtf(s2 * (1.f / 256.f) + 1e-5f);
    float4 gv = *(const float4*)(g + l * 4);
    float4 bv = *(const float4*)(beta + l * 4);
    float4 ov;
    ov.x = dx * rstd * gv.x + bv.x;
    ov.y = dy * rstd * gv.y + bv.y;
    ov.z = dz * rstd * gv.z + bv.z;
    ov.w = dw * rstd * gv.w + bv.w;
    *(float4*)xp = ov;
    if (outh) {
        half4 oh;
        oh[0] = (f16)ov.x; oh[1] = (f16)ov.y; oh[2] = (f16)ov.z; oh[3] = (f16)ov.w;
        *(half4*)(outh + (size_t)r * DM + l * 4) = oh;
    }
}

// ---------------------------------------------------------------------------
// Layer-0 attention, online-softmax prefix scan (fp32 in, f16 packed out).
// ---------------------------------------------------------------------------
__global__ __launch_bounds__(256) void attn0_kernel(
    const float* __restrict__ qkv, f16* __restrict__ ao)
{
    int bp = blockIdx.x;               // b*39 + p
    int b = bp / 39, p = bp % 39;
    int tid = threadIdx.x;
    int h = tid >> 6, l = tid & 63;

    float qv = qkv[(size_t)(b * TS + p) * 768 + h * 64 + l];

    int krow = (l < 39) ? l : 38;
    const float* Kr = qkv + (size_t)(b * TS + krow) * 768 + 256 + h * 64;
    float acc = 0.f;
#pragma unroll
    for (int d4 = 0; d4 < 16; ++d4) {
        float4 k4 = *(const float4*)(Kr + d4 * 4);
        acc += __shfl(qv, d4 * 4 + 0) * k4.x;
        acc += __shfl(qv, d4 * 4 + 1) * k4.y;
        acc += __shfl(qv, d4 * 4 + 2) * k4.z;
        acc += __shfl(qv, d4 * 4 + 3) * k4.w;
    }
    float s = acc * 0.125f;

    float m = -1e30f, lsum = 0.f, o = 0.f;
    for (int t = p; t < TM1; ++t) {
        float st = __shfl(s, t);
        float mnew = fmaxf(m, st);
        float c = __expf(m - mnew);
        float e = __expf(st - mnew);
        lsum = lsum * c + e;
        float vv = qkv[(size_t)(b * TS + t) * 768 + 512 + h * 64 + l];
        o = o * c + e * vv;
        m = mnew;
        int row = ((t * (t + 1)) >> 1) + p;
        ao[((size_t)row * 32 + b) * DM + h * 64 + l] = (f16)(o / lsum);
    }
}

// ---------------------------------------------------------------------------
// Layer-1 attention. Block per (t,b): 4 waves = 4 heads; q = Wq(f16)@h1 row;
// scores lane=key over f16 K; PV lane=dim over f16 V.
// ---------------------------------------------------------------------------
__global__ __launch_bounds__(256) void attn1_kernel(
    const float* __restrict__ h1, const f16* __restrict__ kv1,
    const f16* __restrict__ Wq, const float* __restrict__ bq,
    float* __restrict__ ao1)
{
    int tb = blockIdx.x;
    int t = tb >> 5, b = tb & 31;
    int tid = threadIdx.x;
    int h = tid >> 6, l = tid & 63;
    int tri = (t * (t + 1)) >> 1;
    __shared__ float h1r[DM];
    h1r[tid] = h1[((size_t)(tri + t) * 32 + b) * DM + tid];
    __syncthreads();

    float q = bq[h * 64 + l];
    const half8* w8 = (const half8*)(Wq + (size_t)(h * 64 + l) * DM);
#pragma unroll 8
    for (int c = 0; c < 32; ++c) {
        half8 ww = w8[c];
#pragma unroll
        for (int j = 0; j < 8; ++j)
            q += (float)ww[j] * h1r[c * 8 + j];
    }

    int kr = (l <= t) ? l : t;
    const f16* Kp = kv1 + ((size_t)(tri + kr) * 32 + b) * 512 + h * 64;
    float sc = 0.f;
#pragma unroll
    for (int c = 0; c < 8; ++c) {
        half8 k8 = *(const half8*)(Kp + c * 8);
#pragma unroll
        for (int j = 0; j < 8; ++j)
            sc += __shfl(q, c * 8 + j) * (float)k8[j];
    }
    sc = (l <= t) ? sc * 0.125f : -1e30f;
    float m = sc;
#pragma unroll
    for (int o = 32; o; o >>= 1) m = fmaxf(m, __shfl_xor(m, o));
    float e = (l <= t) ? __expf(sc - m) : 0.f;
    float ss = e;
#pragma unroll
    for (int o = 32; o; o >>= 1) ss += __shfl_xor(ss, o);
    float a = e / ss;

    float o = 0.f;
    for (int k = 0; k <= t; ++k) {
        float ak = __shfl(a, k);
        o += ak * (float)kv1[((size_t)(tri + k) * 32 + b) * 512 + 256 + h * 64 + l];
    }
    ao1[(size_t)tb * DM + h * 64 + l] = o;
}

// ---------------------------------------------------------------------------
// per (t,b): u = fus_w2^T @ cls_w[tok]; cpb = ctx@w1c^T + fus_b1;
//            s = fus_b2 . cls_w[tok] + cls_b[tok]
// ---------------------------------------------------------------------------
__global__ __launch_bounds__(256) void fuse_prep(
    const float* __restrict__ ctx, const int* __restrict__ tokens,
    const float* __restrict__ fw1, const float* __restrict__ fb1,
    const float* __restrict__ fw2, const float* __restrict__ fb2,
    const float* __restrict__ clsw, const float* __restrict__ clsb,
    float* __restrict__ cpb, float* __restrict__ u, float* __restrict__ sv)
{
    int tb = blockIdx.x;               // t*32+b
    int t = tb >> 5, b = tb & 31;
    int j = threadIdx.x;
    __shared__ float cw[DM];
    __shared__ float cr[DM];
    __shared__ float red[4];
    int tok = tokens[b * TS + t];
    cw[j] = clsw[(size_t)tok * DM + j];
    cr[j] = ctx[(size_t)tb * DM + j];
    __syncthreads();
    float uj = 0.f;
    for (int m = 0; m < DM; ++m) uj += fw2[m * DM + j] * cw[m];
    u[(size_t)tb * DM + j] = uj;
    float c = fb1[j];
    const float4* w1c = (const float4*)(fw1 + (size_t)j * (DINO + DM) + DINO);
    for (int d4 = 0; d4 < 64; ++d4) {
        float4 wv = w1c[d4];
        c += wv.x * cr[d4 * 4] + wv.y * cr[d4 * 4 + 1] +
             wv.z * cr[d4 * 4 + 2] + wv.w * cr[d4 * 4 + 3];
    }
    cpb[(size_t)tb * DM + j] = c;
    float s = fb2[j] * cw[j];
#pragma unroll
    for (int o = 32; o; o >>= 1) s += __shfl_xor(s, o);
    if ((j & 63) == 0) red[j >> 6] = s;
    __syncthreads();
    if (j == 0) sv[tb] = red[0] + red[1] + red[2] + red[3] + clsb[tok];
}

// ---------------------------------------------------------------------------
// Fast gelu: AS 7.1.26 erf, |err| <= 1.5e-7.
// ---------------------------------------------------------------------------
__device__ __forceinline__ float gelu_f(float x)
{
    float ax = fabsf(x);
    float z  = ax * 0.70710678118654752440f;
    float tt = __builtin_amdgcn_rcpf(1.f + 0.3275911f * z);
    float pl = ((((1.061405429f * tt - 1.453152027f) * tt + 1.421413741f) * tt
                 - 0.284496736f) * tt + 0.254829592f) * tt;
    float E  = 1.f - pl * __expf(-z * z);
    return 0.5f * x + 0.5f * ax * E;
}

// ---------------------------------------------------------------------------
// out[b,p,t] = sigmoid( sum_k gelu(pp+cpb)*u + s )
// ---------------------------------------------------------------------------
__global__ __launch_bounds__(256) void final_out(
    const f16* __restrict__ pp, const float* __restrict__ cpb,
    const float* __restrict__ u, const float* __restrict__ sv,
    float* __restrict__ out)
{
    int bp = blockIdx.x;               // b*256+p
    int b = bp >> 8;
    int tid = threadIdx.x;
    int w = tid >> 6, l = tid & 63;
    const f16* ppr = pp + (size_t)bp * DM + l * 4;
    float p0 = (float)ppr[0], p1 = (float)ppr[1];
    float p2 = (float)ppr[2], p3 = (float)ppr[3];
    for (int t = w; t < TS; t += 4) {
        int tb = t * 32 + b;
        float4 cp = *(const float4*)(cpb + (size_t)tb * DM + l * 4);
        float4 uu = *(const float4*)(u + (size_t)tb * DM + l * 4);
        float v = gelu_f(p0 + cp.x) * uu.x + gelu_f(p1 + cp.y) * uu.y +
                  gelu_f(p2 + cp.z) * uu.z + gelu_f(p3 + cp.w) * uu.w;
#pragma unroll
        for (int off = 32; off; off >>= 1) v += __shfl_xor(v, off);
        if (l == 0) out[(size_t)bp * TS + t] = 1.f / (1.f + __expf(-(v + sv[tb])));
    }
}

// ---------------------------------------------------------------------------
// Launcher
// ---------------------------------------------------------------------------
extern "C" void kernel_launch(void* const* d_in, const int* in_sizes, int n_in,
                              void* d_out, int out_size, void* d_ws, size_t ws_size,
                              hipStream_t stream)
{
    (void)in_sizes; (void)n_in; (void)out_size;
    const float* patches   = (const float*)d_in[0];
    const int*   tokens    = (const int*)  d_in[1];
    const float* embedding = (const float*)d_in[2];
    const float* pos_emb   = (const float*)d_in[3];
    const float* in_proj_w = (const float*)d_in[4];
    const float* in_proj_b = (const float*)d_in[5];
    const float* out_proj_w= (const float*)d_in[6];
    const float* out_proj_b= (const float*)d_in[7];
    const float* lin1_w    = (const float*)d_in[8];
    const float* lin1_b    = (const float*)d_in[9];
    const float* lin2_w    = (const float*)d_in[10];
    const float* lin2_b    = (const float*)d_in[11];
    const float* ln1_g     = (const float*)d_in[12];
    const float* ln1_b     = (const float*)d_in[13];
    const float* ln2_g     = (const float*)d_in[14];
    const float* ln2_b     = (const float*)d_in[15];
    const float* fus_w1    = (const float*)d_in[16];
    const float* fus_b1    = (const float*)d_in[17];
    const float* fus_w2    = (const float*)d_in[18];
    const float* fus_b2    = (const float*)d_in[19];
    const float* cls_w     = (const float*)d_in[20];
    const float* cls_b     = (const float*)d_in[21];

    if (ws_size < (size_t)WS_FLOATS * 4) return;

    float* ws   = (float*)d_ws;
    float* emb  = ws + OFF_EMB;
    f16*   embh = (f16*)(ws + OFF_EMBH);
    float* qkv0 = ws + OFF_QKV0;
    float* x1   = ws + OFF_X1;
    f16*   x1h  = (f16*)(ws + OFF_X1H);
    float* h1   = ws + OFF_H1;
    f16*   h1h  = (f16*)(ws + OFF_H1H);
    float* big  = ws + OFF_BIG;
    f16*   ao0h = (f16*)big;          // 24960*256 f16 (dead after out-proj)
    f16*   kv1h = (f16*)big;          // 24960*512 f16
    float* ao1  = ws + OFF_AO1;
    float* x2   = ws + OFF_X2;
    float* ff2  = ws + OFF_FF2;
    float* ctx  = ws + OFF_CTX;
    f16*   pph  = (f16*)(ws + OFF_PPH);
    float* cpb  = ws + OFF_CPB;
    float* u    = ws + OFF_U;
    float* svec = ws + OFF_S;
    f16*   wqkvh= (f16*)(ws + OFF_WQKVH);
    f16*   wq1h = (f16*)(ws + OFF_WQ1H);
    f16*   kvwh = (f16*)(ws + OFF_KVWH);
    f16*   woh  = (f16*)(ws + OFF_WOH);
    f16*   l1wh = (f16*)(ws + OFF_L1WH);
    f16*   l2wh = (f16*)(ws + OFF_L2WH);
    f16*   w1ph = (f16*)(ws + OFF_W1PH);
    int*   map1 = (int*)(ws + OFF_MAP);
    int*   map2 = map1 + NTOK;

    prep_kernel<<<5602, 256, 0, stream>>>(
        tokens, embedding, pos_emb, in_proj_w, out_proj_w, lin1_w, lin2_w, fus_w1,
        emb, embh, wqkvh, wq1h, kvwh, woh, l1wh, l2wh, w1ph, map1, map2, ctx);

    // ---- Layer 0 ----
    // QKV: M=1280(20x64), N=768(6), K=256
    gemm_x<64, f16, false, false><<<dim3(6, 20), 256, 0, stream>>>(
        embh, DM, wqkvh, DM, in_proj_b, qkv0, 768, DM);
    attn0_kernel<<<NQ2, 256, 0, stream>>>(qkv0, ao0h);
    // out-proj (A-resident): A=ao0h fetched once, N=256 (2 chunks)
    gemm_ar<256, 2, false><<<390, 256, 0, stream>>>(
        ao0h, woh, out_proj_b, x1, DM);
    ln_kernel<<<6240, 256, 0, stream>>>(x1, emb, map1, ln1_g, ln1_b, NTOK, x1h);
    // fused FF: lin1+lin2, ff1 never materialized
    ff_fused<<<390, 256, 0, stream>>>(x1h, l1wh, lin1_b, l2wh, lin2_b, h1);
    ln_kernel<<<6240, 256, 0, stream>>>(h1, x1, nullptr, ln2_g, ln2_b, NTOK, h1h);

    // ---- Layer 1 ----
    // K/V (A-resident): A=h1h fetched once, N=512 (4 chunks) -> f16 packed
    gemm_ar<256, 4, true><<<390, 256, 0, stream>>>(
        h1h, kvwh, in_proj_b + 768 + 256, kv1h, 512);
    attn1_kernel<<<NQ2, 256, 0, stream>>>(
        h1, kv1h, wq1h, in_proj_b + 768, ao1);
    gemm_nt<false><<<dim3(4, 20), 256, 0, stream>>>(
        ao1, DM, out_proj_w + DM * DM, DM, out_proj_b + DM, x2, DM, NQ2, DM, DM);
    ln_kernel<<<312, 256, 0, stream>>>(x2, h1, map2, ln1_g + DM, ln1_b + DM, NQ2, nullptr);
    gemm_nt<true><<<dim3(16, 20), 256, 0, stream>>>(
        x2, DM, lin1_w + DFF * DM, DM, lin1_b + DFF, ff2, DFF, NQ2, DFF, DM);
    gemm_nt<false><<<dim3(4, 20), 256, 0, stream>>>(
        ff2, DFF, lin2_w + DM * DFF, DFF, lin2_b + DM, ctx + BB * DM, DM, NQ2, DM, DFF);
    ln_kernel<<<312, 256, 0, stream>>>(ctx + BB * DM, x2, nullptr, ln2_g + DM, ln2_b + DM, NQ2, nullptr);

    // ---- Fusion head ----
    // pp: M=8192(128x64), N=256(2), K=384 (A fp32 reg-convert)
    gemm_x<64, float, false, true><<<dim3(2, 128), 256, 0, stream>>>(
        patches, DINO, w1ph, DINO, nullptr, pph, DM, DINO);
    fuse_prep<<<TS * BB, 256, 0, stream>>>(
        ctx, tokens, fus_w1, fus_b1, fus_w2, fus_b2, cls_w, cls_b, cpb, u, svec);
    final_out<<<BB * NPATCH, 256, 0, stream>>>(pph, cpb, u, svec, (float*)d_out);
}

// Round 9
// 565.614 us; speedup vs baseline: 1.1024x; 1.0623x over previous
//
#include <hip/hip_runtime.h>
#include <math.h>

// ---------------------------------------------------------------------------
// Problem constants
// ---------------------------------------------------------------------------
#define DM    256     // D_MODEL
#define NH    4
#define HD    64
#define TS    40
#define TM1   39
#define BB    32
#define DFF   1024
#define DINO  384
#define NPATCH 256
#define VOCAB 4096

#define NTOK  24960   // 780*32 packed (t, p<=t, b) tokens
#define NQ2   1248    // 39*32

typedef _Float16 f16;
typedef __attribute__((ext_vector_type(8))) _Float16 half8;  // MFMA A/B frag
typedef __attribute__((ext_vector_type(4))) _Float16 half4;
typedef __attribute__((ext_vector_type(4))) float f32x4;

// ---------------------------------------------------------------------------
// Workspace layout (float offsets), 121.2 MB total.
// Residual/LN chain fp32 (round-3 lesson). Heavy aliasing:
//  - region A [0,983040): embh | emb | qkvh (all dead after layer-0 attn/LN1)
//  - x1h region aliases pph (pp launched after lin1)
//  - big hosts ao0h -> ff1h -> kv1h sequentially, plus ALL the small layer-1
//    and fusion-head buffers in its tail (free once kv1h shrinks usage).
// ---------------------------------------------------------------------------
#define OFF_EMBH   0u          /* f16 1280*256  -> 163840 */
#define OFF_EMB    163840u     /* f32 1280*256     327680 */
#define OFF_QKVH   491520u     /* f16 1280*768  -> 491520 */
#define OFF_X1     983040u     /* f32 24960*256   6389760 */
#define OFF_X1H    7372800u    /* f16 24960*256 -> 3194880 (pph aliases) */
#define OFF_H1     10567680u   /* f32 24960*256   6389760 */
#define OFF_BIG    16957440u   /* 12779520 */
#define   BO_AO1   6389760u    /* f32 1248*256  319488 (kv1h still alive) */
#define   BO_X2    6709248u    /* f32 1248*256  319488 */
#define   BO_FF2   7028736u    /* f32 1248*1024 1277952 */
#define   BO_CTX   8306688u    /* f32 1280*256  327680 (rows t=0 never read) */
#define   BO_CPB   8634368u    /* f32 1280*256  327680 */
#define   BO_U     8962048u    /* f32 1280*256  327680 */
#define   BO_S     9289728u    /* f32 2048 */
#define OFF_WQKVH  29736960u   /* f16 768*256  ->  98304 */
#define OFF_WQ1H   29835264u   /* f16 256*256  ->  32768 */
#define OFF_KVWH   29868032u   /* f16 512*256  ->  65536 */
#define OFF_WOH    29933568u   /* f16 256*256  ->  32768 */
#define OFF_L1WH   29966336u   /* f16 1024*256 -> 131072 */
#define OFF_L2WH   30097408u   /* f16 256*1024 -> 131072 */
#define OFF_W1PH   30228480u   /* f16 256*384  ->  49152 */
#define OFF_MAP    30277632u   /* int 24960+1248  26208 */
#define WS_FLOATS  30303840u   /* 121.2 MB < 127.57 known-good */

// ---------------------------------------------------------------------------
// prep: embed (fp32+f16) | weight f16 conversions | maps.
// Regions: 327680 | 196608 | 65536 | 131072 | 65536 | 262144 | 262144 | 98304
//          | 25088  -> 1434112 -> grid 5602 x 256.
// ---------------------------------------------------------------------------
__global__ __launch_bounds__(256) void prep_kernel(
    const int* __restrict__ tokens, const float* __restrict__ etab,
    const float* __restrict__ pos,
    const float* __restrict__ ipw, const float* __restrict__ opw,
    const float* __restrict__ l1w, const float* __restrict__ l2w,
    const float* __restrict__ fw1,
    float* __restrict__ emb, f16* __restrict__ embh,
    f16* __restrict__ wqkvh, f16* __restrict__ wq1h, f16* __restrict__ kvwh,
    f16* __restrict__ woh, f16* __restrict__ l1wh, f16* __restrict__ l2wh,
    f16* __restrict__ w1ph,
    int* __restrict__ map1, int* __restrict__ map2)
{
    int i = blockIdx.x * 256 + threadIdx.x;
    if (i < 327680) {                       // embed
        int r = i >> 8, j = i & 255;
        int p = r % TS;
        float v = etab[(size_t)tokens[r] * DM + j] + pos[p * DM + j];
        emb[i] = v; embh[i] = (f16)v;
        return;
    }
    i -= 327680;
    if (i < 196608) { wqkvh[i] = (f16)ipw[i]; return; }                    // L0 qkv W
    i -= 196608;
    if (i < 65536)  { wq1h[i] = (f16)ipw[196608 + i]; return; }            // L1 q W
    i -= 65536;
    if (i < 131072) { kvwh[i] = (f16)ipw[196608 + 65536 + i]; return; }    // L1 kv W
    i -= 131072;
    if (i < 65536)  { woh[i] = (f16)opw[i]; return; }                      // L0 out W
    i -= 65536;
    if (i < 262144) { l1wh[i] = (f16)l1w[i]; return; }                     // L0 lin1 W
    i -= 262144;
    if (i < 262144) { l2wh[i] = (f16)l2w[i]; return; }                     // L0 lin2 W
    i -= 262144;
    if (i < 98304) {                                                       // w1p (strided)
        int r = i / 384, c = i - r * 384;
        w1ph[i] = (f16)fw1[r * 640 + c];
        return;
    }
    i -= 98304;
    if (i < NQ2) {
        int t = i >> 5, b = i & 31;
        map2[i] = ((t * (t + 1)) / 2 + t) * 32 + b;
    }
    if (i < NTOK) {
        int q = i >> 5, b = i & 31;
        int t = 0;
        while (((t + 1) * (t + 2)) / 2 <= q) ++t;
        int p = q - (t * (t + 1)) / 2;
        map1[i] = b * TS + p;
    }
}

// ---------------------------------------------------------------------------
// async 16B/lane global->LDS stage (wave-uniform LDS base) [m97/m104]
// ---------------------------------------------------------------------------
__device__ __forceinline__ void stage16(const f16* g, f16* lbase_wave_uniform) {
    __builtin_amdgcn_global_load_lds(
        (const __attribute__((address_space(1))) void*)g,
        (__attribute__((address_space(3))) void*)lbase_wave_uniform, 16, 0, 0);
}

__device__ __forceinline__ half8 load_frag8(const float* p) {
    float4 a0 = *(const float4*)p;
    float4 a1 = *(const float4*)(p + 4);
    half8 h;
    h[0] = (f16)a0.x; h[1] = (f16)a0.y; h[2] = (f16)a0.z; h[3] = (f16)a0.w;
    h[4] = (f16)a1.x; h[5] = (f16)a1.y; h[6] = (f16)a1.z; h[7] = (f16)a1.w;
    return h;
}

// ---------------------------------------------------------------------------
// MFMA GEMM: BM x 128 tile (BM = 64 or 128), 4 waves, balanced frag mapping
// f = j*4 + w. A = f16 (async stage) or float (reg-convert). fp32 acc.
// M%BM==0, N%128==0, K%64==0. This is the round-6 proven structure.
// ---------------------------------------------------------------------------
template <int BM, typename TA, bool RELU, bool OUTF16>
__global__ __launch_bounds__(256) void gemm_x(
    const TA* __restrict__ A, int lda,
    const f16* __restrict__ B, int ldb,
    const float* __restrict__ bias,
    void* __restrict__ Cv, int ldc, int K)
{
    constexpr int AF  = BM / 8;       // # A frags
    constexpr int TF  = AF + 16;      // total frags
    constexpr int MRE = BM / 32;      // acc rows per wave
    __shared__ __align__(16) f16 lds[TF * 512];
    int tid = threadIdx.x;
    int w = tid >> 6, l = tid & 63;
    int m0 = blockIdx.y * BM, n0 = blockIdx.x << 7;
    int lrow = l & 15;
    int lk8  = (l >> 4) << 3;
    int wm = w >> 1, wn = w & 1;

    f32x4 acc[MRE][4] = {};

    for (int k0 = 0; k0 < K; k0 += 64) {
#pragma unroll
        for (int j = 0; j < TF / 4; ++j) {
            int f = (j << 2) | w;                      // balanced across waves
            if (f < AF) {
                int mi = f >> 1, kc = f & 1;
                const TA* ga = A + (size_t)(m0 + (mi << 4) + lrow) * lda + k0 + (kc << 5) + lk8;
                if constexpr (__is_same(TA, f16)) {
                    stage16(ga, &lds[f << 9]);
                } else {
                    *(half8*)&lds[(f << 9) + (l << 3)] = load_frag8(ga);
                }
            } else {
                int fb = f - AF;
                int nj = fb >> 1, kc = fb & 1;
                const f16* gb = B + (size_t)(n0 + (nj << 4) + lrow) * ldb + k0 + (kc << 5) + lk8;
                stage16(gb, &lds[f << 9]);
            }
        }
        __syncthreads();
#pragma unroll
        for (int kc = 0; kc < 2; ++kc) {
            half8 af[MRE], bfr[4];
#pragma unroll
            for (int i = 0; i < MRE; ++i)
                af[i] = *(half8*)&lds[((((wm * MRE + i) << 1) | kc) << 9) + (l << 3)];
#pragma unroll
            for (int j2 = 0; j2 < 4; ++j2)
                bfr[j2] = *(half8*)&lds[((AF + ((((wn << 2) | j2) << 1) | kc)) << 9) + (l << 3)];
#pragma unroll
            for (int i = 0; i < MRE; ++i)
#pragma unroll
                for (int j2 = 0; j2 < 4; ++j2)
                    acc[i][j2] = __builtin_amdgcn_mfma_f32_16x16x32_f16(
                        af[i], bfr[j2], acc[i][j2], 0, 0, 0);
        }
        __syncthreads();
    }

    int colq = l & 15, rowq = (l >> 4) << 2;           // C/D map [m89/m91]
#pragma unroll
    for (int i = 0; i < MRE; ++i) {
        int gmb = m0 + (wm * MRE + i) * 16 + rowq;
#pragma unroll
        for (int j2 = 0; j2 < 4; ++j2) {
            int gn = n0 + ((wn << 2) | j2) * 16 + colq;
            float bv = bias ? bias[gn] : 0.f;
#pragma unroll
            for (int r = 0; r < 4; ++r) {
                float v = acc[i][j2][r] + bv;
                if (RELU) v = fmaxf(v, 0.f);
                if (OUTF16)
                    ((f16*)Cv)[(size_t)(gmb + r) * ldc + gn] = (f16)v;
                else
                    ((float*)Cv)[(size_t)(gmb + r) * ldc + gn] = v;
            }
        }
    }
}

// ---------------------------------------------------------------------------
// fp32 GEMM (small M) — layer-1 small GEMMs (M=1248).
// ---------------------------------------------------------------------------
template <bool RELU>
__global__ __launch_bounds__(256) void gemm_nt(
    const float* __restrict__ A, int lda,
    const float* __restrict__ B, int ldb,
    const float* __restrict__ bias,
    float* __restrict__ C, int ldc, int M, int N, int K)
{
    __shared__ __align__(16) float As[16][68];
    __shared__ __align__(16) float Bs[16][68];
    int m0 = blockIdx.y << 6, n0 = blockIdx.x << 6;
    int tid = threadIdx.x;
    int tx = tid & 15, ty = tid >> 4;
    int lm = tid >> 2, lk = (tid & 3) << 2;
    float acc[4][4] = {{0.f}};

    for (int k0 = 0; k0 < K; k0 += 16) {
        float4 av;
        int gm = m0 + lm;
        if (gm < M) av = *(const float4*)(A + (size_t)gm * lda + k0 + lk);
        else        av = make_float4(0.f, 0.f, 0.f, 0.f);
        float4 bv = *(const float4*)(B + (size_t)(n0 + lm) * ldb + k0 + lk);
        As[lk + 0][lm] = av.x; As[lk + 1][lm] = av.y;
        As[lk + 2][lm] = av.z; As[lk + 3][lm] = av.w;
        Bs[lk + 0][lm] = bv.x; Bs[lk + 1][lm] = bv.y;
        Bs[lk + 2][lm] = bv.z; Bs[lk + 3][lm] = bv.w;
        __syncthreads();
#pragma unroll
        for (int kk = 0; kk < 16; ++kk) {
            float4 a = *(const float4*)&As[kk][ty << 2];
            float4 b = *(const float4*)&Bs[kk][tx << 2];
            acc[0][0] += a.x * b.x; acc[0][1] += a.x * b.y; acc[0][2] += a.x * b.z; acc[0][3] += a.x * b.w;
            acc[1][0] += a.y * b.x; acc[1][1] += a.y * b.y; acc[1][2] += a.y * b.z; acc[1][3] += a.y * b.w;
            acc[2][0] += a.z * b.x; acc[2][1] += a.z * b.y; acc[2][2] += a.z * b.z; acc[2][3] += a.z * b.w;
            acc[3][0] += a.w * b.x; acc[3][1] += a.w * b.y; acc[3][2] += a.w * b.z; acc[3][3] += a.w * b.w;
        }
        __syncthreads();
    }
#pragma unroll
    for (int i = 0; i < 4; ++i) {
        int gm = m0 + (ty << 2) + i;
        if (gm >= M) continue;
#pragma unroll
        for (int jj = 0; jj < 4; ++jj) {
            int gn = n0 + (tx << 2) + jj;
            float v = acc[i][jj];
            if (bias) v += bias[gn];
            if (RELU) v = fmaxf(v, 0.f);
            C[(size_t)gm * ldc + gn] = v;
        }
    }
}

// ---------------------------------------------------------------------------
// LayerNorm: one WAVE per row, float4 lanes, shuffle reductions.
// Optional f16 dual-store (outh) for downstream GEMM-A consumption.
// ---------------------------------------------------------------------------
__global__ __launch_bounds__(256) void ln_kernel(
    float* __restrict__ X, const float* __restrict__ res,
    const int* __restrict__ map, const float* __restrict__ g,
    const float* __restrict__ beta, int nrows, f16* __restrict__ outh)
{
    int r = blockIdx.x * 4 + (threadIdx.x >> 6);
    if (r >= nrows) return;
    int l = threadIdx.x & 63;
    float* xp = X + (size_t)r * DM + l * 4;
    float4 v = *(float4*)xp;
    if (res) {
        int rr = map ? map[r] : r;
        float4 rv = *(const float4*)(res + (size_t)rr * DM + l * 4);
        v.x += rv.x; v.y += rv.y; v.z += rv.z; v.w += rv.w;
    }
    float s = v.x + v.y + v.z + v.w;
#pragma unroll
    for (int o = 32; o; o >>= 1) s += __shfl_xor(s, o);
    float mean = s * (1.f / 256.f);
    float dx = v.x - mean, dy = v.y - mean, dz = v.z - mean, dw = v.w - mean;
    float s2 = dx * dx + dy * dy + dz * dz + dw * dw;
#pragma unroll
    for (int o = 32; o; o >>= 1) s2 += __shfl_xor(s2, o);
    float rstd = 1.f / sqrtf(s2 * (1.f / 256.f) + 1e-5f);
    float4 gv = *(const float4*)(g + l * 4);
    float4 bv = *(const float4*)(beta + l * 4);
    float4 ov;
    ov.x = dx * rstd * gv.x + bv.x;
    ov.y = dy * rstd * gv.y + bv.y;
    ov.z = dz * rstd * gv.z + bv.z;
    ov.w = dw * rstd * gv.w + bv.w;
    *(float4*)xp = ov;
    if (outh) {
        half4 oh;
        oh[0] = (f16)ov.x; oh[1] = (f16)ov.y; oh[2] = (f16)ov.z; oh[3] = (f16)ov.w;
        *(half4*)(outh + (size_t)r * DM + l * 4) = oh;
    }
}

// ---------------------------------------------------------------------------
// Layer-0 attention, online-softmax prefix scan. qkv is f16 now (half fetch);
// one extra 2^-11 rounding on scores/V vs fp32 — negligible.
// ---------------------------------------------------------------------------
__global__ __launch_bounds__(256) void attn0_kernel(
    const f16* __restrict__ qkv, f16* __restrict__ ao)
{
    int bp = blockIdx.x;               // b*39 + p
    int b = bp / 39, p = bp % 39;
    int tid = threadIdx.x;
    int h = tid >> 6, l = tid & 63;

    float qv = (float)qkv[(size_t)(b * TS + p) * 768 + h * 64 + l];

    int krow = (l < 39) ? l : 38;
    const f16* Kr = qkv + (size_t)(b * TS + krow) * 768 + 256 + h * 64;
    float acc = 0.f;
#pragma unroll
    for (int c = 0; c < 8; ++c) {
        half8 k8 = *(const half8*)(Kr + c * 8);
#pragma unroll
        for (int j = 0; j < 8; ++j)
            acc += __shfl(qv, c * 8 + j) * (float)k8[j];
    }
    float s = acc * 0.125f;

    float m = -1e30f, lsum = 0.f, o = 0.f;
    for (int t = p; t < TM1; ++t) {
        float st = __shfl(s, t);
        float mnew = fmaxf(m, st);
        float c = __expf(m - mnew);
        float e = __expf(st - mnew);
        lsum = lsum * c + e;
        float vv = (float)qkv[(size_t)(b * TS + t) * 768 + 512 + h * 64 + l];
        o = o * c + e * vv;
        m = mnew;
        int row = ((t * (t + 1)) >> 1) + p;
        ao[((size_t)row * 32 + b) * DM + h * 64 + l] = (f16)(o / lsum);
    }
}

// ---------------------------------------------------------------------------
// Layer-1 attention. Block per (t,b): 4 waves = 4 heads; q = Wq(f16)@h1 row;
// scores lane=key over f16 K; PV lane=dim over f16 V.
// ---------------------------------------------------------------------------
__global__ __launch_bounds__(256) void attn1_kernel(
    const float* __restrict__ h1, const f16* __restrict__ kv1,
    const f16* __restrict__ Wq, const float* __restrict__ bq,
    float* __restrict__ ao1)
{
    int tb = blockIdx.x;
    int t = tb >> 5, b = tb & 31;
    int tid = threadIdx.x;
    int h = tid >> 6, l = tid & 63;
    int tri = (t * (t + 1)) >> 1;
    __shared__ float h1r[DM];
    h1r[tid] = h1[((size_t)(tri + t) * 32 + b) * DM + tid];
    __syncthreads();

    float q = bq[h * 64 + l];
    const half8* w8 = (const half8*)(Wq + (size_t)(h * 64 + l) * DM);
#pragma unroll 8
    for (int c = 0; c < 32; ++c) {
        half8 ww = w8[c];
#pragma unroll
        for (int j = 0; j < 8; ++j)
            q += (float)ww[j] * h1r[c * 8 + j];
    }

    int kr = (l <= t) ? l : t;
    const f16* Kp = kv1 + ((size_t)(tri + kr) * 32 + b) * 512 + h * 64;
    float sc = 0.f;
#pragma unroll
    for (int c = 0; c < 8; ++c) {
        half8 k8 = *(const half8*)(Kp + c * 8);
#pragma unroll
        for (int j = 0; j < 8; ++j)
            sc += __shfl(q, c * 8 + j) * (float)k8[j];
    }
    sc = (l <= t) ? sc * 0.125f : -1e30f;
    float m = sc;
#pragma unroll
    for (int o = 32; o; o >>= 1) m = fmaxf(m, __shfl_xor(m, o));
    float e = (l <= t) ? __expf(sc - m) : 0.f;
    float ss = e;
#pragma unroll
    for (int o = 32; o; o >>= 1) ss += __shfl_xor(ss, o);
    float a = e / ss;

    float o = 0.f;
    for (int k = 0; k <= t; ++k) {
        float ak = __shfl(a, k);
        o += ak * (float)kv1[((size_t)(tri + k) * 32 + b) * 512 + 256 + h * 64 + l];
    }
    ao1[(size_t)tb * DM + h * 64 + l] = o;
}

// ---------------------------------------------------------------------------
// per (t,b): u = fus_w2^T @ cls_w[tok]; cpb = ctx@w1c^T + fus_b1;
//            s = fus_b2 . cls_w[tok] + cls_b[tok]
// ctx rows for t==0 are implicit zeros (never written) — handled here.
// ---------------------------------------------------------------------------
__global__ __launch_bounds__(256) void fuse_prep(
    const float* __restrict__ ctx, const int* __restrict__ tokens,
    const float* __restrict__ fw1, const float* __restrict__ fb1,
    const float* __restrict__ fw2, const float* __restrict__ fb2,
    const float* __restrict__ clsw, const float* __restrict__ clsb,
    float* __restrict__ cpb, float* __restrict__ u, float* __restrict__ sv)
{
    int tb = blockIdx.x;               // t*32+b
    int t = tb >> 5, b = tb & 31;
    int j = threadIdx.x;
    __shared__ float cw[DM];
    __shared__ float cr[DM];
    __shared__ float red[4];
    int tok = tokens[b * TS + t];
    cw[j] = clsw[(size_t)tok * DM + j];
    cr[j] = (t == 0) ? 0.f : ctx[(size_t)tb * DM + j];
    __syncthreads();
    float uj = 0.f;
#pragma unroll 8
    for (int m = 0; m < DM; ++m) uj += fw2[m * DM + j] * cw[m];
    u[(size_t)tb * DM + j] = uj;
    float c = fb1[j];
    const float4* w1c = (const float4*)(fw1 + (size_t)j * (DINO + DM) + DINO);
#pragma unroll 8
    for (int d4 = 0; d4 < 64; ++d4) {
        float4 wv = w1c[d4];
        c += wv.x * cr[d4 * 4] + wv.y * cr[d4 * 4 + 1] +
             wv.z * cr[d4 * 4 + 2] + wv.w * cr[d4 * 4 + 3];
    }
    cpb[(size_t)tb * DM + j] = c;
    float s = fb2[j] * cw[j];
#pragma unroll
    for (int o = 32; o; o >>= 1) s += __shfl_xor(s, o);
    if ((j & 63) == 0) red[j >> 6] = s;
    __syncthreads();
    if (j == 0) sv[tb] = red[0] + red[1] + red[2] + red[3] + clsb[tok];
}

// ---------------------------------------------------------------------------
// Fast gelu: AS 7.1.26 erf, |err| <= 1.5e-7.
// ---------------------------------------------------------------------------
__device__ __forceinline__ float gelu_f(float x)
{
    float ax = fabsf(x);
    float z  = ax * 0.70710678118654752440f;
    float tt = __builtin_amdgcn_rcpf(1.f + 0.3275911f * z);
    float pl = ((((1.061405429f * tt - 1.453152027f) * tt + 1.421413741f) * tt
                 - 0.284496736f) * tt + 0.254829592f) * tt;
    float E  = 1.f - pl * __expf(-z * z);
    return 0.5f * x + 0.5f * ax * E;
}

// ---------------------------------------------------------------------------
// out[b,p,t] = sigmoid( sum_k gelu(pp+cpb)*u + s )
// ---------------------------------------------------------------------------
__global__ __launch_bounds__(256) void final_out(
    const f16* __restrict__ pp, const float* __restrict__ cpb,
    const float* __restrict__ u, const float* __restrict__ sv,
    float* __restrict__ out)
{
    int bp = blockIdx.x;               // b*256+p
    int b = bp >> 8;
    int tid = threadIdx.x;
    int w = tid >> 6, l = tid & 63;
    const f16* ppr = pp + (size_t)bp * DM + l * 4;
    float p0 = (float)ppr[0], p1 = (float)ppr[1];
    float p2 = (float)ppr[2], p3 = (float)ppr[3];
    for (int t = w; t < TS; t += 4) {
        int tb = t * 32 + b;
        float4 cp = *(const float4*)(cpb + (size_t)tb * DM + l * 4);
        float4 uu = *(const float4*)(u + (size_t)tb * DM + l * 4);
        float v = gelu_f(p0 + cp.x) * uu.x + gelu_f(p1 + cp.y) * uu.y +
                  gelu_f(p2 + cp.z) * uu.z + gelu_f(p3 + cp.w) * uu.w;
#pragma unroll
        for (int off = 32; off; off >>= 1) v += __shfl_xor(v, off);
        if (l == 0) out[(size_t)bp * TS + t] = 1.f / (1.f + __expf(-(v + sv[tb])));
    }
}

// ---------------------------------------------------------------------------
// Launcher
// ---------------------------------------------------------------------------
extern "C" void kernel_launch(void* const* d_in, const int* in_sizes, int n_in,
                              void* d_out, int out_size, void* d_ws, size_t ws_size,
                              hipStream_t stream)
{
    (void)in_sizes; (void)n_in; (void)out_size;
    const float* patches   = (const float*)d_in[0];
    const int*   tokens    = (const int*)  d_in[1];
    const float* embedding = (const float*)d_in[2];
    const float* pos_emb   = (const float*)d_in[3];
    const float* in_proj_w = (const float*)d_in[4];
    const float* in_proj_b = (const float*)d_in[5];
    const float* out_proj_w= (const float*)d_in[6];
    const float* out_proj_b= (const float*)d_in[7];
    const float* lin1_w    = (const float*)d_in[8];
    const float* lin1_b    = (const float*)d_in[9];
    const float* lin2_w    = (const float*)d_in[10];
    const float* lin2_b    = (const float*)d_in[11];
    const float* ln1_g     = (const float*)d_in[12];
    const float* ln1_b     = (const float*)d_in[13];
    const float* ln2_g     = (const float*)d_in[14];
    const float* ln2_b     = (const float*)d_in[15];
    const float* fus_w1    = (const float*)d_in[16];
    const float* fus_b1    = (const float*)d_in[17];
    const float* fus_w2    = (const float*)d_in[18];
    const float* fus_b2    = (const float*)d_in[19];
    const float* cls_w     = (const float*)d_in[20];
    const float* cls_b     = (const float*)d_in[21];

    if (ws_size < (size_t)WS_FLOATS * 4) return;

    float* ws   = (float*)d_ws;
    f16*   embh = (f16*)(ws + OFF_EMBH);
    float* emb  = ws + OFF_EMB;
    f16*   qkvh = (f16*)(ws + OFF_QKVH);
    float* x1   = ws + OFF_X1;
    f16*   x1h  = (f16*)(ws + OFF_X1H);
    f16*   pph  = (f16*)(ws + OFF_X1H);   // aliases x1h (dead after lin1)
    float* h1   = ws + OFF_H1;
    float* big  = ws + OFF_BIG;
    f16*   ao0h = (f16*)big;              // dead after out-proj
    f16*   ff1h = (f16*)big;              // dead after lin2
    f16*   kv1h = (f16*)big;              // dead after attn1
    float* ao1  = big + BO_AO1;
    float* x2   = big + BO_X2;
    float* ff2  = big + BO_FF2;
    float* ctx  = big + BO_CTX;           // rows t=0 never written/read
    float* cpb  = big + BO_CPB;
    float* u    = big + BO_U;
    float* svec = big + BO_S;
    f16*   wqkvh= (f16*)(ws + OFF_WQKVH);
    f16*   wq1h = (f16*)(ws + OFF_WQ1H);
    f16*   kvwh = (f16*)(ws + OFF_KVWH);
    f16*   woh  = (f16*)(ws + OFF_WOH);
    f16*   l1wh = (f16*)(ws + OFF_L1WH);
    f16*   l2wh = (f16*)(ws + OFF_L2WH);
    f16*   w1ph = (f16*)(ws + OFF_W1PH);
    int*   map1 = (int*)(ws + OFF_MAP);
    int*   map2 = map1 + NTOK;

    prep_kernel<<<5602, 256, 0, stream>>>(
        tokens, embedding, pos_emb, in_proj_w, out_proj_w, lin1_w, lin2_w, fus_w1,
        emb, embh, wqkvh, wq1h, kvwh, woh, l1wh, l2wh, w1ph, map1, map2);

    // ---- Layer 0 ----
    // QKV: M=1280(20x64), N=768(6), K=256 -> f16 out
    gemm_x<64, f16, false, true><<<dim3(6, 20), 256, 0, stream>>>(
        embh, DM, wqkvh, DM, in_proj_b, qkvh, 768, DM);
    attn0_kernel<<<NQ2, 256, 0, stream>>>(qkvh, ao0h);
    // out-proj: M=24960(390x64), N=256(2), K=256 -> x1 fp32
    gemm_x<64, f16, false, false><<<dim3(2, 390), 256, 0, stream>>>(
        ao0h, DM, woh, DM, out_proj_b, x1, DM, DM);
    ln_kernel<<<6240, 256, 0, stream>>>(x1, emb, map1, ln1_g, ln1_b, NTOK, x1h);
    // lin1: M=24960(195x128), N=1024(8), K=256, A f16 async -> ff1h
    gemm_x<128, f16, true, true><<<dim3(8, 195), 256, 0, stream>>>(
        x1h, DM, l1wh, DM, lin1_b, ff1h, DFF, DM);
    // lin2: M=24960(390x64), N=256(2), K=1024 -> h1 fp32
    gemm_x<64, f16, false, false><<<dim3(2, 390), 256, 0, stream>>>(
        ff1h, DFF, l2wh, DFF, lin2_b, h1, DM, DFF);
    ln_kernel<<<6240, 256, 0, stream>>>(h1, x1, nullptr, ln2_g, ln2_b, NTOK, nullptr);

    // ---- Layer 1 ----
    // K/V: M=24960(195x128), N=512(4), K=256, A fp32 reg-convert -> kv1h
    gemm_x<128, float, false, true><<<dim3(4, 195), 256, 0, stream>>>(
        h1, DM, kvwh, DM, in_proj_b + 768 + 256, kv1h, 512, DM);
    // pp: M=8192(128x64), N=256(2), K=384 (x1h region free now -> pph)
    gemm_x<64, float, false, true><<<dim3(2, 128), 256, 0, stream>>>(
        patches, DINO, w1ph, DINO, nullptr, pph, DM, DINO);
    attn1_kernel<<<NQ2, 256, 0, stream>>>(
        h1, kv1h, wq1h, in_proj_b + 768, ao1);
    gemm_nt<false><<<dim3(4, 20), 256, 0, stream>>>(
        ao1, DM, out_proj_w + DM * DM, DM, out_proj_b + DM, x2, DM, NQ2, DM, DM);
    ln_kernel<<<312, 256, 0, stream>>>(x2, h1, map2, ln1_g + DM, ln1_b + DM, NQ2, nullptr);
    gemm_nt<true><<<dim3(16, 20), 256, 0, stream>>>(
        x2, DM, lin1_w + DFF * DM, DM, lin1_b + DFF, ff2, DFF, NQ2, DFF, DM);
    gemm_nt<false><<<dim3(4, 20), 256, 0, stream>>>(
        ff2, DFF, lin2_w + DM * DFF, DFF, lin2_b + DM, ctx + BB * DM, DM, NQ2, DM, DFF);
    ln_kernel<<<312, 256, 0, stream>>>(ctx + BB * DM, x2, nullptr, ln2_g + DM, ln2_b + DM, NQ2, nullptr);

    // ---- Fusion head ----
    fuse_prep<<<TS * BB, 256, 0, stream>>>(
        ctx, tokens, fus_w1, fus_b1, fus_w2, fus_b2, cls_w, cls_b, cpb, u, svec);
    final_out<<<BB * NPATCH, 256, 0, stream>>>(pph, cpb, u, svec, (float*)d_out);
}

// Round 12
// 468.270 us; speedup vs baseline: 1.3315x; 1.2079x over previous
//
#include <hip/hip_runtime.h>
#include <math.h>

// ---------------------------------------------------------------------------
// Problem constants
// ---------------------------------------------------------------------------
#define DM    256     // D_MODEL
#define NH    4
#define HD    64
#define TS    40
#define TM1   39
#define BB    32
#define DFF   1024
#define DINO  384
#define NPATCH 256
#define VOCAB 4096

#define NTOK  24960   // 780*32 packed (t, p<=t, b) tokens
#define NQ2   1248    // 39*32

typedef _Float16 f16;
typedef __attribute__((ext_vector_type(8))) _Float16 half8;  // MFMA A/B frag
typedef __attribute__((ext_vector_type(4))) _Float16 half4;
typedef __attribute__((ext_vector_type(4))) float f32x4;

// ---------------------------------------------------------------------------
// Workspace layout (float offsets), 127.25 MB total (< 127.57 proven budget).
// ROUND-11 POSTMORTEM: weight regions were allocated at HALF size (f16 count
// halved twice) -> cascading overruns + 223 KB write past workspace end ->
// memory fault. This table restores correct sizes: region_floats = f16_elems/2.
// LIFETIME AUDIT (round-10): ff1h spans the ENTIRE big region during
// lin1->lin2, so ctx/cpb/u/svec live in dedicated regions; h1h (written by
// ln2, after lin2) lives in big's tail, disjoint from kv1h head.
// ---------------------------------------------------------------------------
#define OFF_EMBH   0u          /* f16 1280*256  = 327680 h -> 163840 fl */
#define OFF_EMB    163840u     /* f32 1280*256  -> 327680 fl */
#define OFF_QKVH   491520u     /* f16 1280*768  = 983040 h -> 491520 fl */
#define OFF_X1     983040u     /* f32 24960*256 -> 6389760 fl */
#define OFF_X1H    7372800u    /* f16 24960*256 -> 3194880 fl; pph aliases head [0,1048576) fl */
#define OFF_H1     10567680u   /* f32 24960*256 -> 6389760 fl */
#define OFF_BIG    16957440u   /* 12779520 fl */
/* big interior (float offsets from big):
     head [0,6389760)         : ao0h (attn0..outproj0) / ff1h spans ALL of big
                                (lin1..lin2) / kv1h (kv..attn1)
     BT_AO1H  [6389760,6553600)   f16 1280*256, written by attn1
     BT_X2    [6553600,6881280)   f32 1280*256, written by out-proj1
     BT_X2H   [6881280,7045120)   f16 1280*256, written by ln(x2)
     BT_FF2H  [7045120,7700480)   f16 1280*1024, written by lin1-l1
     BT_H1H   [7700480,10895360)  f16 24960*256, written by ln2 (post-lin2),
                                  read by kv-gemm; disjoint from kv1h head. */
#define   BT_AO1H  6389760u
#define   BT_X2    6553600u
#define   BT_X2H   6881280u
#define   BT_FF2H  7045120u
#define   BT_H1H   7700480u
#define OFF_CTX    29736960u   /* f32 1280*256 -> 327680 fl (rows 0..31 zeroed by prep) */
#define OFF_CPB    30064640u   /* f32 1280*256 -> 327680 fl (lin2-l1 pad spill lands here; rewritten) */
#define OFF_U      30392320u   /* f32 1280*256 -> 327680 fl (dedicated — survives ff1h) */
#define OFF_S      30720000u   /* f32 2048 fl */
#define OFF_WQKVH  30722048u   /* f16 768*256  = 196608 h ->  98304 fl */
#define OFF_WQ1H   30820352u   /* f16 256*256  =  65536 h ->  32768 fl */
#define OFF_KVWH   30853120u   /* f16 512*256  = 131072 h ->  65536 fl */
#define OFF_WOH    30918656u   /* f16 256*256  ->  32768 fl */
#define OFF_WOH1   30951424u   /* f16 256*256  ->  32768 fl */
#define OFF_L1WH   30984192u   /* f16 1024*256 -> 131072 fl */
#define OFF_L1WH1  31115264u   /* f16 1024*256 -> 131072 fl */
#define OFF_L2WH   31246336u   /* f16 256*1024 -> 131072 fl */
#define OFF_L2WH1  31377408u   /* f16 256*1024 -> 131072 fl */
#define OFF_W1PH   31508480u   /* f16 256*384  =  98304 h ->  49152 fl */
#define OFF_W1CH   31557632u   /* f16 256*256  ->  32768 fl */
#define OFF_FW2TH  31590400u   /* f16 256*256  ->  32768 fl */
#define OFF_CWGH   31623168u   /* f16 1280*256 = 327680 h -> 163840 fl */
#define OFF_MAP    31787008u   /* int 24960+1248 -> 26208 fl */
#define WS_FLOATS  31813216u   /* = 127.25 MB < 127.57 known-good */

// ---------------------------------------------------------------------------
// prep: embed | all weight f16 conversions | w1p/w1c/fw2t gathers | cls
// gather | s vector | ctx t=0 zeros | maps.
// 2572800 elements -> grid 10050 x 256. Region starts 64-aligned (shuffles).
// ---------------------------------------------------------------------------
__global__ __launch_bounds__(256) void prep_kernel(
    const int* __restrict__ tokens, const float* __restrict__ etab,
    const float* __restrict__ pos,
    const float* __restrict__ ipw, const float* __restrict__ opw,
    const float* __restrict__ l1w, const float* __restrict__ l2w,
    const float* __restrict__ fw1, const float* __restrict__ fw2,
    const float* __restrict__ clsw, const float* __restrict__ clsb,
    const float* __restrict__ fb2,
    float* __restrict__ emb, f16* __restrict__ embh,
    f16* __restrict__ wqkvh, f16* __restrict__ wq1h, f16* __restrict__ kvwh,
    f16* __restrict__ woh, f16* __restrict__ woh1,
    f16* __restrict__ l1wh, f16* __restrict__ l1wh1,
    f16* __restrict__ l2wh, f16* __restrict__ l2wh1,
    f16* __restrict__ w1ph, f16* __restrict__ w1ch, f16* __restrict__ fw2th,
    f16* __restrict__ cwgh, float* __restrict__ sv, float* __restrict__ ctx,
    int* __restrict__ map1, int* __restrict__ map2)
{
    int i = blockIdx.x * 256 + threadIdx.x;
    if (i < 327680) {                       // embed
        int r = i >> 8, j = i & 255;
        int p = r % TS;
        float v = etab[(size_t)tokens[r] * DM + j] + pos[p * DM + j];
        emb[i] = v; embh[i] = (f16)v;
        return;
    }
    i -= 327680;
    if (i < 196608) { wqkvh[i] = (f16)ipw[i]; return; }
    i -= 196608;
    if (i < 65536)  { wq1h[i] = (f16)ipw[196608 + i]; return; }
    i -= 65536;
    if (i < 131072) { kvwh[i] = (f16)ipw[262144 + i]; return; }
    i -= 131072;
    if (i < 65536)  { woh[i]  = (f16)opw[i]; return; }
    i -= 65536;
    if (i < 65536)  { woh1[i] = (f16)opw[65536 + i]; return; }
    i -= 65536;
    if (i < 262144) { l1wh[i]  = (f16)l1w[i]; return; }
    i -= 262144;
    if (i < 262144) { l1wh1[i] = (f16)l1w[262144 + i]; return; }
    i -= 262144;
    if (i < 262144) { l2wh[i]  = (f16)l2w[i]; return; }
    i -= 262144;
    if (i < 262144) { l2wh1[i] = (f16)l2w[262144 + i]; return; }
    i -= 262144;
    if (i < 98304) {                        // w1p (strided gather)
        int r = i / 384, c = i - r * 384;
        w1ph[i] = (f16)fw1[r * 640 + c];
        return;
    }
    i -= 98304;
    if (i < 65536) {                        // w1c (strided gather)
        int n = i >> 8, k = i & 255;
        w1ch[i] = (f16)fw1[n * 640 + 384 + k];
        return;
    }
    i -= 65536;
    if (i < 65536) {                        // fw2 transpose: fw2t[j,k]=fw2[k,j]
        int j = i >> 8, k = i & 255;
        fw2th[i] = (f16)fw2[k * 256 + j];
        return;
    }
    i -= 65536;
    if (i < 327680) {                       // cls gather: cwgh[tb,:] = cls_w[tok(t,b)]
        int tb = i >> 8, j = i & 255;
        int t = tb >> 5, b = tb & 31;
        cwgh[i] = (f16)clsw[(size_t)tokens[b * TS + t] * DM + j];
        return;
    }
    i -= 327680;
    if (i < 81920) {                        // s[tb] = fb2 . cls_w[tok] + clsb[tok]
        int tb = i >> 6, l = i & 63;
        int t = tb >> 5, b = tb & 31;
        int tok = tokens[b * TS + t];
        float a = 0.f;
#pragma unroll
        for (int c = 0; c < 4; ++c)
            a += fb2[l + 64 * c] * clsw[(size_t)tok * DM + l + 64 * c];
#pragma unroll
        for (int o = 32; o; o >>= 1) a += __shfl_xor(a, o);
        if (l == 0) sv[tb] = a + clsb[tok];
        return;
    }
    i -= 81920;
    if (i < 8192) { ctx[i] = 0.f; return; } // ctx rows t=0 (dedicated region)
    i -= 8192;
    if (i < NQ2) {
        int t = i >> 5, b = i & 31;
        map2[i] = ((t * (t + 1)) / 2 + t) * 32 + b;
    }
    if (i < NTOK) {
        int q = i >> 5, b = i & 31;
        int t = 0;
        while (((t + 1) * (t + 2)) / 2 <= q) ++t;
        int p = q - (t * (t + 1)) / 2;
        map1[i] = b * TS + p;
    }
}

// ---------------------------------------------------------------------------
// async 16B/lane global->LDS stage (wave-uniform LDS base) [m97/m104]
// ---------------------------------------------------------------------------
__device__ __forceinline__ void stage16(const f16* g, f16* lbase_wave_uniform) {
    __builtin_amdgcn_global_load_lds(
        (const __attribute__((address_space(1))) void*)g,
        (__attribute__((address_space(3))) void*)lbase_wave_uniform, 16, 0, 0);
}

__device__ __forceinline__ half8 load_frag8(const float* p) {
    float4 a0 = *(const float4*)p;
    float4 a1 = *(const float4*)(p + 4);
    half8 h;
    h[0] = (f16)a0.x; h[1] = (f16)a0.y; h[2] = (f16)a0.z; h[3] = (f16)a0.w;
    h[4] = (f16)a1.x; h[5] = (f16)a1.y; h[6] = (f16)a1.z; h[7] = (f16)a1.w;
    return h;
}

// ---------------------------------------------------------------------------
// MFMA GEMM: BM x 128 tile (BM = 64 or 128), 4 waves, balanced frag mapping
// f = j*4 + w. A = f16 (async stage) or float (reg-convert). fp32 acc.
// M%BM==0, N%128==0, K%64==0. Round-6-proven structure.
// ---------------------------------------------------------------------------
template <int BM, typename TA, bool RELU, bool OUTF16>
__global__ __launch_bounds__(256) void gemm_x(
    const TA* __restrict__ A, int lda,
    const f16* __restrict__ B, int ldb,
    const float* __restrict__ bias,
    void* __restrict__ Cv, int ldc, int K)
{
    constexpr int AF  = BM / 8;       // # A frags
    constexpr int TF  = AF + 16;      // total frags
    constexpr int MRE = BM / 32;      // acc rows per wave
    __shared__ __align__(16) f16 lds[TF * 512];
    int tid = threadIdx.x;
    int w = tid >> 6, l = tid & 63;
    int m0 = blockIdx.y * BM, n0 = blockIdx.x << 7;
    int lrow = l & 15;
    int lk8  = (l >> 4) << 3;
    int wm = w >> 1, wn = w & 1;

    f32x4 acc[MRE][4] = {};

    for (int k0 = 0; k0 < K; k0 += 64) {
#pragma unroll
        for (int j = 0; j < TF / 4; ++j) {
            int f = (j << 2) | w;                      // balanced across waves
            if (f < AF) {
                int mi = f >> 1, kc = f & 1;
                const TA* ga = A + (size_t)(m0 + (mi << 4) + lrow) * lda + k0 + (kc << 5) + lk8;
                if constexpr (__is_same(TA, f16)) {
                    stage16(ga, &lds[f << 9]);
                } else {
                    *(half8*)&lds[(f << 9) + (l << 3)] = load_frag8(ga);
                }
            } else {
                int fb = f - AF;
                int nj = fb >> 1, kc = fb & 1;
                const f16* gb = B + (size_t)(n0 + (nj << 4) + lrow) * ldb + k0 + (kc << 5) + lk8;
                stage16(gb, &lds[f << 9]);
            }
        }
        __syncthreads();
#pragma unroll
        for (int kc = 0; kc < 2; ++kc) {
            half8 af[MRE], bfr[4];
#pragma unroll
            for (int i = 0; i < MRE; ++i)
                af[i] = *(half8*)&lds[((((wm * MRE + i) << 1) | kc) << 9) + (l << 3)];
#pragma unroll
            for (int j2 = 0; j2 < 4; ++j2)
                bfr[j2] = *(half8*)&lds[((AF + ((((wn << 2) | j2) << 1) | kc)) << 9) + (l << 3)];
#pragma unroll
            for (int i = 0; i < MRE; ++i)
#pragma unroll
                for (int j2 = 0; j2 < 4; ++j2)
                    acc[i][j2] = __builtin_amdgcn_mfma_f32_16x16x32_f16(
                        af[i], bfr[j2], acc[i][j2], 0, 0, 0);
        }
        __syncthreads();
    }

    int colq = l & 15, rowq = (l >> 4) << 2;           // C/D map [m89/m91]
#pragma unroll
    for (int i = 0; i < MRE; ++i) {
        int gmb = m0 + (wm * MRE + i) * 16 + rowq;
#pragma unroll
        for (int j2 = 0; j2 < 4; ++j2) {
            int gn = n0 + ((wn << 2) | j2) * 16 + colq;
            float bv = bias ? bias[gn] : 0.f;
#pragma unroll
            for (int r = 0; r < 4; ++r) {
                float v = acc[i][j2][r] + bv;
                if (RELU) v = fmaxf(v, 0.f);
                if (OUTF16)
                    ((f16*)Cv)[(size_t)(gmb + r) * ldc + gn] = (f16)v;
                else
                    ((float*)Cv)[(size_t)(gmb + r) * ldc + gn] = v;
            }
        }
    }
}

// ---------------------------------------------------------------------------
// LayerNorm: one WAVE per row, float4 lanes, shuffle reductions.
// Optional f16 dual-store (outh) for downstream GEMM-A consumption.
// ---------------------------------------------------------------------------
__global__ __launch_bounds__(256) void ln_kernel(
    float* __restrict__ X, const float* __restrict__ res,
    const int* __restrict__ map, const float* __restrict__ g,
    const float* __restrict__ beta, int nrows, f16* __restrict__ outh)
{
    int r = blockIdx.x * 4 + (threadIdx.x >> 6);
    if (r >= nrows) return;
    int l = threadIdx.x & 63;
    float* xp = X + (size_t)r * DM + l * 4;
    float4 v = *(float4*)xp;
    if (res) {
        int rr = map ? map[r] : r;
        float4 rv = *(const float4*)(res + (size_t)rr * DM + l * 4);
        v.x += rv.x; v.y += rv.y; v.z += rv.z; v.w += rv.w;
    }
    float s = v.x + v.y + v.z + v.w;
#pragma unroll
    for (int o = 32; o; o >>= 1) s += __shfl_xor(s, o);
    float mean = s * (1.f / 256.f);
    float dx = v.x - mean, dy = v.y - mean, dz = v.z - mean, dw = v.w - mean;
    float s2 = dx * dx + dy * dy + dz * dz + dw * dw;
#pragma unroll
    for (int o = 32; o; o >>= 1) s2 += __shfl_xor(s2, o);
    float rstd = 1.f / sqrtf(s2 * (1.f / 256.f) + 1e-5f);
    float4 gv = *(const float4*)(g + l * 4);
    float4 bv = *(const float4*)(beta + l * 4);
    float4 ov;
    ov.x = dx * rstd * gv.x + bv.x;
    ov.y = dy * rstd * gv.y + bv.y;
    ov.z = dz * rstd * gv.z + bv.z;
    ov.w = dw * rstd * gv.w + bv.w;
    *(float4*)xp = ov;
    if (outh) {
        half4 oh;
        oh[0] = (f16)ov.x; oh[1] = (f16)ov.y; oh[2] = (f16)ov.z; oh[3] = (f16)ov.w;
        *(half4*)(outh + (size_t)r * DM + l * 4) = oh;
    }
}

// ---------------------------------------------------------------------------
// Layer-0 attention, online-softmax prefix scan (f16 qkv, f16 packed out).
// ---------------------------------------------------------------------------
__global__ __launch_bounds__(256) void attn0_kernel(
    const f16* __restrict__ qkv, f16* __restrict__ ao)
{
    int bp = blockIdx.x;               // b*39 + p
    int b = bp / 39, p = bp % 39;
    int tid = threadIdx.x;
    int h = tid >> 6, l = tid & 63;

    float qv = (float)qkv[(size_t)(b * TS + p) * 768 + h * 64 + l];

    int krow = (l < 39) ? l : 38;
    const f16* Kr = qkv + (size_t)(b * TS + krow) * 768 + 256 + h * 64;
    float acc = 0.f;
#pragma unroll
    for (int c = 0; c < 8; ++c) {
        half8 k8 = *(const half8*)(Kr + c * 8);
#pragma unroll
        for (int j = 0; j < 8; ++j)
            acc += __shfl(qv, c * 8 + j) * (float)k8[j];
    }
    float s = acc * 0.125f;

    float m = -1e30f, lsum = 0.f, o = 0.f;
    for (int t = p; t < TM1; ++t) {
        float st = __shfl(s, t);
        float mnew = fmaxf(m, st);
        float c = __expf(m - mnew);
        float e = __expf(st - mnew);
        lsum = lsum * c + e;
        float vv = (float)qkv[(size_t)(b * TS + t) * 768 + 512 + h * 64 + l];
        o = o * c + e * vv;
        m = mnew;
        int row = ((t * (t + 1)) >> 1) + p;
        ao[((size_t)row * 32 + b) * DM + h * 64 + l] = (f16)(o / lsum);
    }
}

// ---------------------------------------------------------------------------
// Layer-1 attention. Block per (t,b): 4 waves = 4 heads; q = Wq(f16)@h1 row;
// scores lane=key over f16 K; PV lane=dim over f16 V. Output f16.
// ---------------------------------------------------------------------------
__global__ __launch_bounds__(256) void attn1_kernel(
    const float* __restrict__ h1, const f16* __restrict__ kv1,
    const f16* __restrict__ Wq, const float* __restrict__ bq,
    f16* __restrict__ ao1)
{
    int tb = blockIdx.x;
    int t = tb >> 5, b = tb & 31;
    int tid = threadIdx.x;
    int h = tid >> 6, l = tid & 63;
    int tri = (t * (t + 1)) >> 1;
    __shared__ float h1r[DM];
    h1r[tid] = h1[((size_t)(tri + t) * 32 + b) * DM + tid];
    __syncthreads();

    float q = bq[h * 64 + l];
    const half8* w8 = (const half8*)(Wq + (size_t)(h * 64 + l) * DM);
#pragma unroll 8
    for (int c = 0; c < 32; ++c) {
        half8 ww = w8[c];
#pragma unroll
        for (int j = 0; j < 8; ++j)
            q += (float)ww[j] * h1r[c * 8 + j];
    }

    int kr = (l <= t) ? l : t;
    const f16* Kp = kv1 + ((size_t)(tri + kr) * 32 + b) * 512 + h * 64;
    float sc = 0.f;
#pragma unroll
    for (int c = 0; c < 8; ++c) {
        half8 k8 = *(const half8*)(Kp + c * 8);
#pragma unroll
        for (int j = 0; j < 8; ++j)
            sc += __shfl(q, c * 8 + j) * (float)k8[j];
    }
    sc = (l <= t) ? sc * 0.125f : -1e30f;
    float m = sc;
#pragma unroll
    for (int o = 32; o; o >>= 1) m = fmaxf(m, __shfl_xor(m, o));
    float e = (l <= t) ? __expf(sc - m) : 0.f;
    float ss = e;
#pragma unroll
    for (int o = 32; o; o >>= 1) ss += __shfl_xor(ss, o);
    float a = e / ss;

    float o = 0.f;
    for (int k = 0; k <= t; ++k) {
        float ak = __shfl(a, k);
        o += ak * (float)kv1[((size_t)(tri + k) * 32 + b) * 512 + 256 + h * 64 + l];
    }
    ao1[(size_t)tb * DM + h * 64 + l] = (f16)o;
}

// ---------------------------------------------------------------------------
// Fast gelu via A&S 7.1.25 erf (|err| <= 5e-4, no exp — one transcendental):
// erf(z) ~= 1 - 1/(1 + a1 z + a2 z^2 + a3 z^3 + a4 z^4)^4
// Worst-case logit shift ~3e-4 -> prob shift <1e-4, far under threshold.
// ---------------------------------------------------------------------------
__device__ __forceinline__ float gelu_f(float x)
{
    float ax = fabsf(x);
    float z  = ax * 0.70710678118654752440f;
    float d  = 1.f + z * (0.278393f + z * (0.230389f + z * (0.000972f + z * 0.078108f)));
    float d2 = d * d;
    float E  = 1.f - __builtin_amdgcn_rcpf(d2 * d2);
    return 0.5f * x + 0.5f * ax * E;
}

// ---------------------------------------------------------------------------
// out[b,p,t] = sigmoid( sum_k gelu(pp+cpb)*u + s )
// ---------------------------------------------------------------------------
__global__ __launch_bounds__(256) void final_out(
    const f16* __restrict__ pp, const float* __restrict__ cpb,
    const float* __restrict__ u, const float* __restrict__ sv,
    float* __restrict__ out)
{
    int bp = blockIdx.x;               // b*256+p
    int b = bp >> 8;
    int tid = threadIdx.x;
    int w = tid >> 6, l = tid & 63;
    const f16* ppr = pp + (size_t)bp * DM + l * 4;
    float p0 = (float)ppr[0], p1 = (float)ppr[1];
    float p2 = (float)ppr[2], p3 = (float)ppr[3];
    for (int t = w; t < TS; t += 4) {
        int tb = t * 32 + b;
        float4 cp = *(const float4*)(cpb + (size_t)tb * DM + l * 4);
        float4 uu = *(const float4*)(u + (size_t)tb * DM + l * 4);
        float v = gelu_f(p0 + cp.x) * uu.x + gelu_f(p1 + cp.y) * uu.y +
                  gelu_f(p2 + cp.z) * uu.z + gelu_f(p3 + cp.w) * uu.w;
#pragma unroll
        for (int off = 32; off; off >>= 1) v += __shfl_xor(v, off);
        if (l == 0) out[(size_t)bp * TS + t] = 1.f / (1.f + __expf(-(v + sv[tb])));
    }
}

// ---------------------------------------------------------------------------
// Launcher
// ---------------------------------------------------------------------------
extern "C" void kernel_launch(void* const* d_in, const int* in_sizes, int n_in,
                              void* d_out, int out_size, void* d_ws, size_t ws_size,
                              hipStream_t stream)
{
    (void)in_sizes; (void)n_in; (void)out_size;
    const float* patches   = (const float*)d_in[0];
    const int*   tokens    = (const int*)  d_in[1];
    const float* embedding = (const float*)d_in[2];
    const float* pos_emb   = (const float*)d_in[3];
    const float* in_proj_w = (const float*)d_in[4];
    const float* in_proj_b = (const float*)d_in[5];
    const float* out_proj_w= (const float*)d_in[6];
    const float* out_proj_b= (const float*)d_in[7];
    const float* lin1_w    = (const float*)d_in[8];
    const float* lin1_b    = (const float*)d_in[9];
    const float* lin2_w    = (const float*)d_in[10];
    const float* lin2_b    = (const float*)d_in[11];
    const float* ln1_g     = (const float*)d_in[12];
    const float* ln1_b     = (const float*)d_in[13];
    const float* ln2_g     = (const float*)d_in[14];
    const float* ln2_b     = (const float*)d_in[15];
    const float* fus_w1    = (const float*)d_in[16];
    const float* fus_b1    = (const float*)d_in[17];
    const float* fus_w2    = (const float*)d_in[18];
    const float* fus_b2    = (const float*)d_in[19];
    const float* cls_w     = (const float*)d_in[20];
    const float* cls_b     = (const float*)d_in[21];

    if (ws_size < (size_t)WS_FLOATS * 4) return;

    float* ws   = (float*)d_ws;
    f16*   embh = (f16*)(ws + OFF_EMBH);
    float* emb  = ws + OFF_EMB;
    f16*   qkvh = (f16*)(ws + OFF_QKVH);
    float* x1   = ws + OFF_X1;
    f16*   x1h  = (f16*)(ws + OFF_X1H);
    f16*   pph  = (f16*)(ws + OFF_X1H);   // aliases x1h head (x1h dead after lin1)
    float* h1   = ws + OFF_H1;
    float* big  = ws + OFF_BIG;
    f16*   ao0h = (f16*)big;              // head; dead after out-proj0
    f16*   ff1h = (f16*)big;              // spans ALL of big; dead after lin2
    f16*   kv1h = (f16*)big;              // head; dead after attn1
    f16*   ao1h = (f16*)(big + BT_AO1H);
    float* x2   = big + BT_X2;
    f16*   x2h  = (f16*)(big + BT_X2H);
    f16*   ff2h = (f16*)(big + BT_FF2H);
    f16*   h1h  = (f16*)(big + BT_H1H);   // written by ln2 (post-lin2)
    float* ctx  = ws + OFF_CTX;           // dedicated; rows 0..31 zeroed by prep
    float* cpb  = ws + OFF_CPB;
    float* u    = ws + OFF_U;
    float* svec = ws + OFF_S;
    f16*   wqkvh= (f16*)(ws + OFF_WQKVH);
    f16*   wq1h = (f16*)(ws + OFF_WQ1H);
    f16*   kvwh = (f16*)(ws + OFF_KVWH);
    f16*   woh  = (f16*)(ws + OFF_WOH);
    f16*   woh1 = (f16*)(ws + OFF_WOH1);
    f16*   l1wh = (f16*)(ws + OFF_L1WH);
    f16*   l1wh1= (f16*)(ws + OFF_L1WH1);
    f16*   l2wh = (f16*)(ws + OFF_L2WH);
    f16*   l2wh1= (f16*)(ws + OFF_L2WH1);
    f16*   w1ph = (f16*)(ws + OFF_W1PH);
    f16*   w1ch = (f16*)(ws + OFF_W1CH);
    f16*   fw2th= (f16*)(ws + OFF_FW2TH);
    f16*   cwgh = (f16*)(ws + OFF_CWGH);
    int*   map1 = (int*)(ws + OFF_MAP);
    int*   map2 = map1 + NTOK;

    prep_kernel<<<10050, 256, 0, stream>>>(
        tokens, embedding, pos_emb, in_proj_w, out_proj_w, lin1_w, lin2_w,
        fus_w1, fus_w2, cls_w, cls_b, fus_b2,
        emb, embh, wqkvh, wq1h, kvwh, woh, woh1, l1wh, l1wh1, l2wh, l2wh1,
        w1ph, w1ch, fw2th, cwgh, svec, ctx, map1, map2);

    // u = cwg @ fw2t^T : M=1280(20x64), N=256(2), K=256 (u dedicated — safe early)
    gemm_x<64, f16, false, false><<<dim3(2, 20), 256, 0, stream>>>(
        cwgh, DM, fw2th, DM, nullptr, u, DM, DM);

    // ---- Layer 0 ----
    gemm_x<64, f16, false, true><<<dim3(6, 20), 256, 0, stream>>>(
        embh, DM, wqkvh, DM, in_proj_b, qkvh, 768, DM);
    attn0_kernel<<<NQ2, 256, 0, stream>>>(qkvh, ao0h);
    gemm_x<64, f16, false, false><<<dim3(2, 390), 256, 0, stream>>>(
        ao0h, DM, woh, DM, out_proj_b, x1, DM, DM);
    ln_kernel<<<6240, 256, 0, stream>>>(x1, emb, map1, ln1_g, ln1_b, NTOK, x1h);
    gemm_x<128, f16, true, true><<<dim3(8, 195), 256, 0, stream>>>(
        x1h, DM, l1wh, DM, lin1_b, ff1h, DFF, DM);
    gemm_x<64, f16, false, false><<<dim3(2, 390), 256, 0, stream>>>(
        ff1h, DFF, l2wh, DFF, lin2_b, h1, DM, DFF);
    // ln2 dual-stores h1h into big tail (ff1h dead now)
    ln_kernel<<<6240, 256, 0, stream>>>(h1, x1, nullptr, ln2_g, ln2_b, NTOK, h1h);

    // pp: M=8192(128x64), N=256(2), K=384 (x1h head free -> pph)
    gemm_x<64, float, false, true><<<dim3(2, 128), 256, 0, stream>>>(
        patches, DINO, w1ph, DINO, nullptr, pph, DM, DINO);

    // ---- Layer 1 ----
    // K/V: A = h1h f16 async, N=512(4) -> kv1h (big head; disjoint from h1h tail)
    gemm_x<128, f16, false, true><<<dim3(4, 195), 256, 0, stream>>>(
        h1h, DM, kvwh, DM, in_proj_b + 768 + 256, kv1h, 512, DM);
    attn1_kernel<<<NQ2, 256, 0, stream>>>(
        h1, kv1h, wq1h, in_proj_b + 768, ao1h);
    // out-proj1 (MFMA, M padded to 1280; pad rows garbage, never read)
    gemm_x<64, f16, false, false><<<dim3(2, 20), 256, 0, stream>>>(
        ao1h, DM, woh1, DM, out_proj_b + DM, x2, DM, DM);
    ln_kernel<<<312, 256, 0, stream>>>(x2, h1, map2, ln1_g + DM, ln1_b + DM, NQ2, x2h);
    gemm_x<64, f16, true, true><<<dim3(8, 20), 256, 0, stream>>>(
        x2h, DM, l1wh1, DM, lin1_b + DFF, ff2h, DFF, DM);
    // pad rows spill 8192 floats into cpb head; cpb-gemm rewrites cpb below
    gemm_x<64, f16, false, false><<<dim3(2, 20), 256, 0, stream>>>(
        ff2h, DFF, l2wh1, DFF, lin2_b + DM, ctx + BB * DM, DM, DFF);
    ln_kernel<<<312, 256, 0, stream>>>(ctx + BB * DM, x2, nullptr, ln2_g + DM, ln2_b + DM, NQ2, nullptr);

    // cpb = ctx @ w1c^T + fus_b1 : M=1280(20x64), N=256(2), K=256
    gemm_x<64, float, false, false><<<dim3(2, 20), 256, 0, stream>>>(
        ctx, DM, w1ch, DM, fus_b1, cpb, DM, DM);

    final_out<<<BB * NPATCH, 256, 0, stream>>>(pph, cpb, u, svec, (float*)d_out);
}